// Round 15
// baseline (598.335 us; speedup 1.0000x reference)
//
#include <hip/hip_runtime.h>
#include <hip/hip_bf16.h>

#define NN 20000
#define DD 512
#define EE 150000
#define NH 2560  // stacked GEMM width: 4*512 (W_i) + 512 (Wl_top)

typedef __attribute__((ext_vector_type(8))) short short8;
typedef __attribute__((ext_vector_type(4))) float floatx4;

static __device__ __forceinline__ float bfbits2f(unsigned short u) {
    unsigned int x = ((unsigned int)u) << 16;
    return __uint_as_float(x);
}

#define GLOAD_LDS16(g, l)                                                        \
    __builtin_amdgcn_global_load_lds((const __attribute__((address_space(1))) void*)(g), \
                                     (__attribute__((address_space(3))) void*)(l), 16, 0, 0)

// ---------------- fused preprocessing: convert x, zero deg4, wal8 ----------------
#define PRE_CONV 10000
#define PRE_ZERO 313
#define PRE_WAL 64
__global__ __launch_bounds__(256)
void k_preproc(const float* __restrict__ x, __hip_bfloat16* __restrict__ x_bf,
               int* __restrict__ deg4,
               const float* __restrict__ W0, const float* __restrict__ W1,
               const float* __restrict__ W2, const float* __restrict__ W3,
               const float* __restrict__ al0, const float* __restrict__ al1,
               const float* __restrict__ al2, const float* __restrict__ al3,
               const float* __restrict__ ar0, const float* __restrict__ ar1,
               const float* __restrict__ ar2, const float* __restrict__ ar3,
               float* __restrict__ wal8) {
    int b = blockIdx.x;
    int tid = threadIdx.x;
    if (b < PRE_CONV) {
        int i = b * 256 + tid;
        float4 v = ((const float4*)x)[i];
        union { __hip_bfloat16 bb[4]; ushort4 u; } cv;
        cv.bb[0] = __float2bfloat16(v.x);
        cv.bb[1] = __float2bfloat16(v.y);
        cv.bb[2] = __float2bfloat16(v.z);
        cv.bb[3] = __float2bfloat16(v.w);
        *(ushort4*)(x_bf + 4l * i) = cv.u;
    } else if (b < PRE_CONV + PRE_ZERO) {
        int i = (b - PRE_CONV) * 256 + tid;
        if (i < 4 * NN) deg4[i] = 0;
    } else {
        int vk = b - PRE_CONV - PRE_ZERO;
        int v = vk >> 3, kg = vk & 7;
        int rel = v & 3;
        const float* Wp = rel == 0 ? W0 : rel == 1 ? W1 : rel == 2 ? W2 : W3;
        const float* vec;
        if (v < 4) vec = rel == 0 ? al0 : rel == 1 ? al1 : rel == 2 ? al2 : al3;
        else vec = rel == 0 ? ar0 : rel == 1 ? ar1 : rel == 2 ? ar2 : ar3;
        int wave = tid >> 6, lane = tid & 63;
#pragma unroll 1
        for (int i = 0; i < 16; i++) {
            int k = kg * 64 + wave * 16 + i;
            float s = 0.f;
#pragma unroll
            for (int c = 0; c < 8; c++) s += Wp[(size_t)k * 512 + c * 64 + lane] * vec[c * 64 + lane];
#pragma unroll
            for (int off = 32; off > 0; off >>= 1) s += __shfl_xor(s, off);
            if (lane == 0) wal8[v * 512 + k] = s;
        }
    }
}

// ---------------- 6x 512x512 transpose + convert to bf16, one launch ----------------
__global__ __launch_bounds__(1024)
void k_transpose6(const float* __restrict__ W0, const float* __restrict__ W1,
                  const float* __restrict__ W2, const float* __restrict__ W3,
                  const float* __restrict__ Wl, __hip_bfloat16* __restrict__ Bt_all,
                  __hip_bfloat16* __restrict__ WlTb) {
    __shared__ float tile[32][33];
    int z = blockIdx.z;
    const float* in = z == 0 ? W0 : z == 1 ? W1 : z == 2 ? W2 : z == 3 ? W3
                      : (z == 4 ? Wl : Wl + (size_t)DD * DD);
    __hip_bfloat16* out = z < 5 ? Bt_all + (size_t)z * DD * DD : WlTb;
    int bx = blockIdx.x * 32;
    int by = blockIdx.y * 32;
    int tx = threadIdx.x, ty = threadIdx.y;
    tile[ty][tx] = in[(by + ty) * 512 + bx + tx];
    __syncthreads();
    out[(bx + ty) * 512 + by + tx] = __float2bfloat16(tile[tx][ty]);
}

// ---------------- el/er for all 4 relations from x (wal8 algebra) ----------------
__global__ __launch_bounds__(256)
void k_elr8(const __hip_bfloat16* __restrict__ x_bf, const float* __restrict__ wal8,
            float* __restrict__ el4, float* __restrict__ er4) {
    int wave = threadIdx.x >> 6, lane = threadIdx.x & 63;
    int r = blockIdx.x * 4 + wave;
    uint4 xv = *(const uint4*)(x_bf + (size_t)r * DD + lane * 8);
    const unsigned short* xs = (const unsigned short*)&xv;
    float xf[8];
#pragma unroll
    for (int j = 0; j < 8; j++) xf[j] = bfbits2f(xs[j]);
    float s[8];
#pragma unroll
    for (int v = 0; v < 8; v++) {
        const float* wp = wal8 + v * 512 + lane * 8;
        s[v] = xf[0] * wp[0] + xf[1] * wp[1] + xf[2] * wp[2] + xf[3] * wp[3] +
               xf[4] * wp[4] + xf[5] * wp[5] + xf[6] * wp[6] + xf[7] * wp[7];
    }
#pragma unroll
    for (int off = 32; off > 0; off >>= 1)
#pragma unroll
        for (int v = 0; v < 8; v++) s[v] += __shfl_xor(s[v], off);
    if (lane == 0) {
#pragma unroll
        for (int rel = 0; rel < 4; rel++) {
            el4[rel * NN + r] = s[rel];
            er4[rel * NN + r] = s[4 + rel];
        }
    }
}

// ---------------- GEMM (chain): 128x128, BK=64, dbuf 2-phase + COALESCED staging ---
// R12: R8's proven 256^2 dbuf stage-ahead schedule, halved to 128^2 (64KB LDS,
// 2 blocks/CU). R4's earlier 128^2-dbuf regression predates the coalescing fix
// (staging was 4x transaction-bound then; occupancy loss dominated). Same macros,
// same XOR chunk space (BK=64), same barrier placement as the verified mega.
// mode 1: t_next = bf16(relu(C + xwl) + gnext)   (chain mid)
// mode 2: outf = relu(C + xwl) fp32              (chain last)
__global__ __launch_bounds__(512)
void k_gemm512(const __hip_bfloat16* __restrict__ A, const __hip_bfloat16* __restrict__ Bt,
               __hip_bfloat16* __restrict__ Cb, const __hip_bfloat16* __restrict__ xwl,
               const __hip_bfloat16* __restrict__ gnext, __hip_bfloat16* __restrict__ t_next,
               float* __restrict__ outf, int c_ld, int M, int CT, int mode) {
    const int RT = (M + 127) >> 7;
    const int xcd = blockIdx.x & 7;
    const int k_ = blockIdx.x >> 3;
    const int ctile = k_ % CT;
    const int rtile = (k_ / CT) * 8 + xcd;
    if (rtile >= RT) return;

    __shared__ __hip_bfloat16 As0[128 * 64];  // 16 KB each; row-major [128][64], chunks XOR-swz
    __shared__ __hip_bfloat16 Bs0[128 * 64];
    __shared__ __hip_bfloat16 As1[128 * 64];
    __shared__ __hip_bfloat16 Bs1[128 * 64];
    const int tid = threadIdx.x;
    const int lane = tid & 63;
    const int wave = tid >> 6;
    const int row0 = rtile * 128;
    const int col0 = ctile * 128;
    const int wm = (wave >> 2) * 64;   // 0 or 64
    const int wn = (wave & 3) * 32;    // 0,32,64,96
    const int q8 = lane >> 4;
    const int l15 = lane & 15;
    const int l7 = l15 & 7;

    // coalesced staging: wave w instr j stages 8 rows (w*16 + j*8 + rsub)
    const int rsub = lane >> 3;                // row within 8-row group
    const int csw = (lane & 7) ^ rsub;         // XOR-swizzled source chunk (involution)
    const __hip_bfloat16* aBase = A + (size_t)csw * 8;
    const __hip_bfloat16* bBase = Bt + (size_t)csw * 8;

#define STAGE128(k0, AL, BL)                                                              \
    {                                                                                     \
        _Pragma("unroll") for (int j = 0; j < 2; j++) {                                   \
            int arow = row0 + wave * 16 + j * 8 + rsub;                                   \
            if (arow >= M) arow = M - 1;                                                  \
            int brow = col0 + wave * 16 + j * 8 + rsub;                                   \
            GLOAD_LDS16(aBase + (size_t)arow * DD + (k0),                                 \
                        (AL) + ((wave * 16 + j * 8) * 64) + (size_t)lane * 8);            \
            GLOAD_LDS16(bBase + (size_t)brow * DD + (k0),                                 \
                        (BL) + ((wave * 16 + j * 8) * 64) + (size_t)lane * 8);            \
        }                                                                                 \
    }

#define COMPUTE128(AS, BS)                                                          \
    {                                                                               \
        _Pragma("unroll") for (int kk = 0; kk < 2; kk++) {                          \
            const int cp = ((kk * 4 + q8) ^ l7) * 8;                                \
            short8 af[4], bfr[2];                                                   \
            _Pragma("unroll") for (int mi = 0; mi < 4; mi++)                        \
                af[mi] = *(const short8*)((AS) +                                    \
                    (size_t)(wm + mi * 16 + l15) * 64 + cp);                        \
            _Pragma("unroll") for (int ni = 0; ni < 2; ni++)                        \
                bfr[ni] = *(const short8*)((BS) +                                   \
                    (size_t)(wn + ni * 16 + l15) * 64 + cp);                        \
            _Pragma("unroll") for (int mi = 0; mi < 4; mi++)                        \
                _Pragma("unroll") for (int ni = 0; ni < 2; ni++)                    \
                    acc[mi][ni] = __builtin_amdgcn_mfma_f32_16x16x32_bf16(          \
                        af[mi], bfr[ni], acc[mi][ni], 0, 0, 0);                     \
        }                                                                           \
    }

    floatx4 acc[4][2];
#pragma unroll
    for (int a = 0; a < 4; a++)
#pragma unroll
        for (int b = 0; b < 2; b++) acc[a][b] = (floatx4){0.f, 0.f, 0.f, 0.f};

    // prologue: stage K-tile 0 into buf0
    STAGE128(0, As0, Bs0)
    __syncthreads();

    // 8 K-tiles (DD=512, BK=64), 2 per iteration; stage t+1 BEFORE computing t
#pragma unroll 1
    for (int t0 = 0; t0 < 8; t0 += 2) {
        STAGE128(t0 * 64 + 64, As1, Bs1)       // tile t0+1 -> buf1 (always exists)
        COMPUTE128(As0, Bs0)                   // tile t0 from buf0
        __syncthreads();                       // vmcnt(0): t0+1 loads landed under compute
        if (t0 < 6) STAGE128(t0 * 64 + 128, As0, Bs0)  // tile t0+2 -> buf0
        COMPUTE128(As1, Bs1)                   // tile t0+1 from buf1
        __syncthreads();
    }
#undef STAGE128
#undef COMPUTE128

#pragma unroll
    for (int mi = 0; mi < 4; mi++)
#pragma unroll
        for (int ni = 0; ni < 2; ni++)
#pragma unroll
            for (int r = 0; r < 4; r++) {
                int grow = row0 + wm + mi * 16 + q8 * 4 + r;
                int gcol = col0 + wn + ni * 16 + l15;
                if (grow < M) {
                    float v = acc[mi][ni][r];
                    if (mode == 0) {
                        Cb[(size_t)grow * c_ld + gcol] = __float2bfloat16(v);
                    } else {
                        v += bfbits2f(
                            *(const unsigned short*)(xwl + (size_t)grow * NH + 2048 + gcol));
                        v = v > 0.f ? v : 0.f;
                        size_t idx = (size_t)grow * DD + gcol;
                        if (mode == 1) {
                            v += bfbits2f(*(const unsigned short*)(gnext + idx));
                            t_next[idx] = __float2bfloat16(v);
                        } else {
                            outf[idx] = v;
                        }
                    }
                }
            }
}

// ---------------- MEGA-GEMM: 256x256, BK=64, dbuf 2-phase, COALESCED+SWIZZLED ------
// R8 WIN: 160->97us, MfmaUtil 13->22, conflicts 0. FROZEN.
__global__ __launch_bounds__(512)
void k_gemm256(const __hip_bfloat16* __restrict__ A, const __hip_bfloat16* __restrict__ Bt,
               __hip_bfloat16* __restrict__ Cb, int c_ld, int M, int CT) {
    const int RT = (M + 255) >> 8;
    const int xcd = blockIdx.x & 7;
    const int k_ = blockIdx.x >> 3;
    const int ctile = k_ % CT;
    const int rtile = (k_ / CT) * 8 + xcd;
    if (rtile >= RT) return;

    __shared__ __hip_bfloat16 As0[256 * 64];  // 32 KB each; row-major [row][64], chunks XOR-swz
    __shared__ __hip_bfloat16 Bs0[256 * 64];
    __shared__ __hip_bfloat16 As1[256 * 64];
    __shared__ __hip_bfloat16 Bs1[256 * 64];
    const int tid = threadIdx.x;
    const int lane = tid & 63;
    const int wave = tid >> 6;
    const int row0 = rtile * 256;
    const int col0 = ctile * 256;
    const int wm = (wave >> 2) * 128;  // 0 or 128
    const int wn = (wave & 3) * 64;    // 0,64,128,192
    const int q8 = lane >> 4;
    const int l15 = lane & 15;
    const int l7 = l15 & 7;

    // staging: wave w, instr j stages 8 rows (w*32 + j*8 + rsub), lane reads chunk csw
    const int rsub = lane >> 3;                // row within 8-row group
    const int csw = (lane & 7) ^ rsub;         // XOR-swizzled source chunk (involution)
    const __hip_bfloat16* aBase = A + (size_t)csw * 8;
    const __hip_bfloat16* bBase = Bt + (size_t)csw * 8;

#define STAGE256(k0, AL, BL)                                                              \
    {                                                                                     \
        _Pragma("unroll") for (int j = 0; j < 4; j++) {                                   \
            int arow = row0 + wave * 32 + j * 8 + rsub;                                   \
            if (arow >= M) arow = M - 1;                                                  \
            int brow = col0 + wave * 32 + j * 8 + rsub;                                   \
            GLOAD_LDS16(aBase + (size_t)arow * DD + (k0),                                 \
                        (AL) + ((wave * 32 + j * 8) * 64) + (size_t)lane * 8);            \
            GLOAD_LDS16(bBase + (size_t)brow * DD + (k0),                                 \
                        (BL) + ((wave * 32 + j * 8) * 64) + (size_t)lane * 8);            \
        }                                                                                 \
    }

#define COMPUTE256(AS, BS)                                                          \
    {                                                                               \
        _Pragma("unroll") for (int kk = 0; kk < 2; kk++) {                          \
            const int cp = ((kk * 4 + q8) ^ l7) * 8;                                \
            short8 af[8], bfr[4];                                                   \
            _Pragma("unroll") for (int mi = 0; mi < 8; mi++)                        \
                af[mi] = *(const short8*)((AS) +                                    \
                    (size_t)(wm + mi * 16 + l15) * 64 + cp);                        \
            _Pragma("unroll") for (int ni = 0; ni < 4; ni++)                        \
                bfr[ni] = *(const short8*)((BS) +                                   \
                    (size_t)(wn + ni * 16 + l15) * 64 + cp);                        \
            _Pragma("unroll") for (int mi = 0; mi < 8; mi++)                        \
                _Pragma("unroll") for (int ni = 0; ni < 4; ni++)                    \
                    acc[mi][ni] = __builtin_amdgcn_mfma_f32_16x16x32_bf16(          \
                        af[mi], bfr[ni], acc[mi][ni], 0, 0, 0);                     \
        }                                                                           \
    }

    floatx4 acc[8][4];
#pragma unroll
    for (int a = 0; a < 8; a++)
#pragma unroll
        for (int b = 0; b < 4; b++) acc[a][b] = (floatx4){0.f, 0.f, 0.f, 0.f};

    // prologue: stage K-tile 0 into buf0; syncthreads drains vmcnt + barriers
    STAGE256(0, As0, Bs0)
    __syncthreads();

    // 8 K-tiles (DD=512, BK=64), 2 per iteration; stage t+1 BEFORE computing t
#pragma unroll 1
    for (int t0 = 0; t0 < 8; t0 += 2) {
        STAGE256(t0 * 64 + 64, As1, Bs1)       // tile t0+1 -> buf1 (always exists)
        COMPUTE256(As0, Bs0)                   // tile t0 from buf0
        __syncthreads();                       // vmcnt(0): t0+1 loads landed under compute
        if (t0 < 6) STAGE256(t0 * 64 + 128, As0, Bs0)  // tile t0+2 -> buf0
        COMPUTE256(As1, Bs1)                   // tile t0+1 from buf1
        __syncthreads();
    }
#undef STAGE256
#undef COMPUTE256

#pragma unroll
    for (int mi = 0; mi < 8; mi++)
#pragma unroll
        for (int ni = 0; ni < 4; ni++)
#pragma unroll
            for (int r = 0; r < 4; r++) {
                int grow = row0 + wm + mi * 16 + q8 * 4 + r;
                int gcol = col0 + wn + ni * 16 + l15;
                if (grow < M) Cb[(size_t)grow * c_ld + gcol] = __float2bfloat16(acc[mi][ni][r]);
            }
}

// ---------------- CSR build (batched over 4 relations) ----------------
__global__ void k_count4(const int* __restrict__ e0, const int* __restrict__ e1,
                         const int* __restrict__ e2, const int* __restrict__ e3,
                         int* __restrict__ deg4) {
    int g = blockIdx.x * blockDim.x + threadIdx.x;
    if (g >= 4 * EE) return;
    int rel = g / EE;
    int e = g - rel * EE;
    const int* ed = rel == 0 ? e0 : rel == 1 ? e1 : rel == 2 ? e2 : e3;
    atomicAdd(&deg4[rel * NN + ed[EE + e]], 1);
}

__global__ __launch_bounds__(1024)
void k_scan4(const int* __restrict__ deg4, int* __restrict__ rp4, int* __restrict__ cur4) {
    const int rel = blockIdx.x;
    const int* deg = deg4 + rel * NN;
    int* row_ptr = rp4 + rel * (NN + 1);
    int* cursor = cur4 + rel * NN;
    __shared__ int sm[1024];
    int t = threadIdx.x;
    const int CH = 20;
    int begin = t * CH;
    int end = begin + CH;
    if (end > NN) end = NN;
    int s = 0;
    if (begin < NN)
        for (int i = begin; i < end; i++) s += deg[i];
    sm[t] = s;
    __syncthreads();
    for (int off = 1; off < 1024; off <<= 1) {
        int v = (t >= off) ? sm[t - off] : 0;
        __syncthreads();
        sm[t] += v;
        __syncthreads();
    }
    int run = sm[t] - s;
    if (begin < NN) {
        for (int i = begin; i < end; i++) {
            row_ptr[i] = run;
            cursor[i] = run;
            run += deg[i];
        }
        if (end == NN) row_ptr[NN] = run;
    }
}

__global__ void k_scatter4(const int* __restrict__ e0, const int* __restrict__ e1,
                           const int* __restrict__ e2, const int* __restrict__ e3,
                           int* __restrict__ cur4, int* __restrict__ csr4) {
    int g = blockIdx.x * blockDim.x + threadIdx.x;
    if (g >= 4 * EE) return;
    int rel = g / EE;
    int e = g - rel * EE;
    const int* ed = rel == 0 ? e0 : rel == 1 ? e1 : rel == 2 ? e2 : e3;
    int dst = ed[EE + e];
    int pos = atomicAdd(&cur4[rel * NN + dst], 1);
    csr4[rel * EE + pos] = ed[e];
}

// ---------------- BATCHED edge-softmax + aggregate (+bias), wave per dst ----------
// R9 version (86.6us, occupancy 74%) restored: R10's readlane pipeline regressed
// (VALU 39->51, occ 74->57, dur +3.3us) -> agg4 is at the random-gather BW floor.
__global__ __launch_bounds__(256)
void k_agg4(const int* __restrict__ rp4, const int* __restrict__ csr4,
            const float* __restrict__ el4, const float* __restrict__ er4,
            const __hip_bfloat16* __restrict__ h_all, const float* __restrict__ bias,
            __hip_bfloat16* __restrict__ gat4, float* __restrict__ alpha4) {
    const int rel = blockIdx.y;
    const int* row_ptr = rp4 + rel * (NN + 1);
    const int* csr_src = csr4 + (size_t)rel * EE;
    const float* el = el4 + rel * NN;
    const float* er = er4 + rel * NN;
    const __hip_bfloat16* h = h_all + (size_t)rel * 512;
    float* alpha_tmp = alpha4 + (size_t)rel * EE;

    int d = (blockIdx.x * blockDim.x + threadIdx.x) >> 6;
    int lane = threadIdx.x & 63;
    if (d >= NN) return;
    int s0 = row_ptr[d], s1 = row_ptr[d + 1];
    int deg = s1 - s0;
    int base = lane * 8;
    float acc[8] = {0.f, 0.f, 0.f, 0.f, 0.f, 0.f, 0.f, 0.f};

    if (deg <= 64) {
        int sv = 0;
        float av = 0.f;
        if (lane < deg) sv = csr_src[s0 + lane];
        float erd = er[d];
        float v = -1e30f;
        if (lane < deg) {
            float e = el[sv] + erd;
            v = e >= 0.f ? e : 0.2f * e;
        }
        float m = v;
#pragma unroll
        for (int off = 32; off > 0; off >>= 1) m = fmaxf(m, __shfl_xor(m, off));
        float wgt = (lane < deg) ? __expf(v - m) : 0.f;
        float s = wgt;
#pragma unroll
        for (int off = 32; off > 0; off >>= 1) s += __shfl_xor(s, off);
        av = wgt / s;
        int t = 0;
        for (; t + 3 < deg; t += 4) {
            int sA = __shfl(sv, t), sB = __shfl(sv, t + 1);
            int sC = __shfl(sv, t + 2), sD = __shfl(sv, t + 3);
            float aA = __shfl(av, t), aB = __shfl(av, t + 1);
            float aC = __shfl(av, t + 2), aD = __shfl(av, t + 3);
            uint4 hv0 = *(const uint4*)(h + (size_t)sA * NH + base);
            uint4 hv1 = *(const uint4*)(h + (size_t)sB * NH + base);
            uint4 hv2 = *(const uint4*)(h + (size_t)sC * NH + base);
            uint4 hv3 = *(const uint4*)(h + (size_t)sD * NH + base);
            const unsigned short* h0 = (const unsigned short*)&hv0;
            const unsigned short* h1 = (const unsigned short*)&hv1;
            const unsigned short* h2 = (const unsigned short*)&hv2;
            const unsigned short* h3 = (const unsigned short*)&hv3;
#pragma unroll
            for (int k = 0; k < 8; k++)
                acc[k] += aA * bfbits2f(h0[k]) + aB * bfbits2f(h1[k]) + aC * bfbits2f(h2[k]) +
                          aD * bfbits2f(h3[k]);
        }
        for (; t < deg; t++) {
            int sA = __shfl(sv, t);
            float aA = __shfl(av, t);
            uint4 hv0 = *(const uint4*)(h + (size_t)sA * NH + base);
            const unsigned short* h0 = (const unsigned short*)&hv0;
#pragma unroll
            for (int k = 0; k < 8; k++) acc[k] += aA * bfbits2f(h0[k]);
        }
    } else {
        float erd = er[d];
        float m = -1e30f;
        for (int j = s0 + lane; j < s1; j += 64) {
            float e = el[csr_src[j]] + erd;
            e = e >= 0.f ? e : 0.2f * e;
            alpha_tmp[j] = e;
            m = fmaxf(m, e);
        }
#pragma unroll
        for (int off = 32; off > 0; off >>= 1) m = fmaxf(m, __shfl_xor(m, off));
        float s = 0.f;
        for (int j = s0 + lane; j < s1; j += 64) {
            float wv = __expf(alpha_tmp[j] - m);
            alpha_tmp[j] = wv;
            s += wv;
        }
#pragma unroll
        for (int off = 32; off > 0; off >>= 1) s += __shfl_xor(s, off);
        float inv = 1.f / s;
        for (int j0 = 0; j0 < deg; j0 += 64) {
            int cnt = deg - j0;
            if (cnt > 64) cnt = 64;
            int sv = 0;
            float av = 0.f;
            if (lane < cnt) {
                sv = csr_src[s0 + j0 + lane];
                av = alpha_tmp[s0 + j0 + lane] * inv;
            }
            for (int t = 0; t < cnt; t++) {
                int sA = __shfl(sv, t);
                float aA = __shfl(av, t);
                uint4 hv0 = *(const uint4*)(h + (size_t)sA * NH + base);
                const unsigned short* h0 = (const unsigned short*)&hv0;
#pragma unroll
                for (int k = 0; k < 8; k++) acc[k] += aA * bfbits2f(h0[k]);
            }
        }
    }

    float4 b0 = *(const float4*)(bias + base);
    float4 b1 = *(const float4*)(bias + base + 4);
    acc[0] += b0.x; acc[1] += b0.y; acc[2] += b0.z; acc[3] += b0.w;
    acc[4] += b1.x; acc[5] += b1.y; acc[6] += b1.z; acc[7] += b1.w;
    union { __hip_bfloat16 b[8]; uint4 u; } cv;
#pragma unroll
    for (int k = 0; k < 8; k++) cv.b[k] = __float2bfloat16(acc[k]);
    *(uint4*)(gat4 + (size_t)rel * NN * DD + (size_t)d * DD + base) = cv.u;
}

extern "C" void kernel_launch(void* const* d_in, const int* in_sizes, int n_in,
                              void* d_out, int out_size, void* d_ws, size_t ws_size,
                              hipStream_t stream) {
    const float* x = (const float*)d_in[0];
    const int* edges[4] = {(const int*)d_in[1], (const int*)d_in[5], (const int*)d_in[9],
                           (const int*)d_in[13]};
    const float* W[4] = {(const float*)d_in[2], (const float*)d_in[6], (const float*)d_in[10],
                         (const float*)d_in[14]};
    const float* al[4] = {(const float*)d_in[3], (const float*)d_in[7], (const float*)d_in[11],
                          (const float*)d_in[15]};
    const float* ar[4] = {(const float*)d_in[4], (const float*)d_in[8], (const float*)d_in[12],
                          (const float*)d_in[16]};
    const float* Wl = (const float*)d_in[17];
    const float* bias = (const float*)d_in[18];
    float* out = (float*)d_out;

    char* w = (char*)d_ws;
    auto alloc = [&](size_t bytes) {
        char* p = w;
        w += (bytes + 255) & ~(size_t)255;
        return p;
    };
    __hip_bfloat16* x_bf = (__hip_bfloat16*)alloc((size_t)NN * DD * 2);
    __hip_bfloat16* h_all = (__hip_bfloat16*)alloc((size_t)NN * NH * 2);   // [h0..h3|xwl]
    __hip_bfloat16* gat4 = (__hip_bfloat16*)alloc((size_t)4 * NN * DD * 2);
    __hip_bfloat16* t_A = (__hip_bfloat16*)alloc((size_t)NN * DD * 2);
    __hip_bfloat16* t_B = (__hip_bfloat16*)alloc((size_t)NN * DD * 2);
    __hip_bfloat16* Bt_all = (__hip_bfloat16*)alloc((size_t)NH * DD * 2);  // [W0..W3,WlTop]^T
    __hip_bfloat16* WlTb = (__hip_bfloat16*)alloc((size_t)DD * DD * 2);
    float* wal8 = (float*)alloc((size_t)8 * 512 * 4);
    float* el4 = (float*)alloc((size_t)4 * NN * 4);
    float* er4 = (float*)alloc((size_t)4 * NN * 4);
    int* deg4 = (int*)alloc((size_t)4 * NN * 4);
    int* rp4 = (int*)alloc((size_t)4 * (NN + 1) * 4);
    int* cur4 = (int*)alloc((size_t)4 * NN * 4);
    int* csr4 = (int*)alloc((size_t)4 * EE * 4);
    float* alpha4 = (float*)alloc((size_t)4 * EE * 4);

    // fused preprocessing: convert x, zero deg4, wal8 = W@al / W@ar
    k_preproc<<<PRE_CONV + PRE_ZERO + PRE_WAL, 256, 0, stream>>>(
        x, x_bf, deg4, W[0], W[1], W[2], W[3], al[0], al[1], al[2], al[3], ar[0], ar[1], ar[2],
        ar[3], wal8);
    dim3 tb(32, 32), tg6(16, 16, 6);
    k_transpose6<<<tg6, tb, 0, stream>>>(W[0], W[1], W[2], W[3], Wl, Bt_all, WlTb);

    // CSR for all 4 relations
    k_count4<<<(4 * EE + 255) / 256, 256, 0, stream>>>(edges[0], edges[1], edges[2], edges[3], deg4);
    k_scan4<<<4, 1024, 0, stream>>>(deg4, rp4, cur4);
    k_scatter4<<<(4 * EE + 255) / 256, 256, 0, stream>>>(edges[0], edges[1], edges[2], edges[3],
                                                         cur4, csr4);

    // el/er from x directly
    k_elr8<<<NN / 4, 256, 0, stream>>>(x_bf, wal8, el4, er4);

    // MEGA-GEMM: h_all = x @ [W0..W3|Wl_top], 256x256 tiles, CT=10, coalesced staging
    const int RT256p8 = (((NN + 255) / 256 + 7) / 8) * 8;  // 80
    k_gemm256<<<RT256p8 * 10, 512, 0, stream>>>(x_bf, Bt_all, h_all, NH, NN, 10);

    // batched aggregate (+bias), wave per dst
    dim3 gagg((NN * 64 + 255) / 256, 4);
    k_agg4<<<gagg, 256, 0, stream>>>(rp4, csr4, el4, er4, h_all, bias, gat4, alpha4);

    // serial chain: t_{i+1} = relu(t_i @ Wl_bot + xwl) + gat4[i+1]; last writes fp32 out
    const int RT128p8 = (((NN + 127) / 128 + 7) / 8) * 8;  // 160
    const int NB = RT128p8 * 4;
    k_gemm512<<<NB, 512, 0, stream>>>(gat4, WlTb, nullptr, h_all, gat4 + (size_t)1 * NN * DD, t_A,
                                      nullptr, DD, NN, 4, 1);
    k_gemm512<<<NB, 512, 0, stream>>>(t_A, WlTb, nullptr, h_all, gat4 + (size_t)2 * NN * DD, t_B,
                                      nullptr, DD, NN, 4, 1);
    k_gemm512<<<NB, 512, 0, stream>>>(t_B, WlTb, nullptr, h_all, gat4 + (size_t)3 * NN * DD, t_A,
                                      nullptr, DD, NN, 4, 1);
    k_gemm512<<<NB, 512, 0, stream>>>(t_A, WlTb, nullptr, h_all, nullptr, nullptr, out, DD, NN, 4,
                                      2);
}

// Round 16
// 533.788 us; speedup vs baseline: 1.1209x; 1.1209x over previous
//
#include <hip/hip_runtime.h>
#include <hip/hip_bf16.h>

#define NN 20000
#define DD 512
#define EE 150000
#define NH 2560  // stacked GEMM width: 4*512 (W_i) + 512 (Wl_top)

typedef __attribute__((ext_vector_type(8))) short short8;
typedef __attribute__((ext_vector_type(4))) float floatx4;

static __device__ __forceinline__ float bfbits2f(unsigned short u) {
    unsigned int x = ((unsigned int)u) << 16;
    return __uint_as_float(x);
}

#define GLOAD_LDS16(g, l)                                                        \
    __builtin_amdgcn_global_load_lds((const __attribute__((address_space(1))) void*)(g), \
                                     (__attribute__((address_space(3))) void*)(l), 16, 0, 0)

// ---------------- fused preprocessing: convert x, zero deg4, wal8 ----------------
#define PRE_CONV 10000
#define PRE_ZERO 313
#define PRE_WAL 64
__global__ __launch_bounds__(256)
void k_preproc(const float* __restrict__ x, __hip_bfloat16* __restrict__ x_bf,
               int* __restrict__ deg4,
               const float* __restrict__ W0, const float* __restrict__ W1,
               const float* __restrict__ W2, const float* __restrict__ W3,
               const float* __restrict__ al0, const float* __restrict__ al1,
               const float* __restrict__ al2, const float* __restrict__ al3,
               const float* __restrict__ ar0, const float* __restrict__ ar1,
               const float* __restrict__ ar2, const float* __restrict__ ar3,
               float* __restrict__ wal8) {
    int b = blockIdx.x;
    int tid = threadIdx.x;
    if (b < PRE_CONV) {
        int i = b * 256 + tid;
        float4 v = ((const float4*)x)[i];
        union { __hip_bfloat16 bb[4]; ushort4 u; } cv;
        cv.bb[0] = __float2bfloat16(v.x);
        cv.bb[1] = __float2bfloat16(v.y);
        cv.bb[2] = __float2bfloat16(v.z);
        cv.bb[3] = __float2bfloat16(v.w);
        *(ushort4*)(x_bf + 4l * i) = cv.u;
    } else if (b < PRE_CONV + PRE_ZERO) {
        int i = (b - PRE_CONV) * 256 + tid;
        if (i < 4 * NN) deg4[i] = 0;
    } else {
        int vk = b - PRE_CONV - PRE_ZERO;
        int v = vk >> 3, kg = vk & 7;
        int rel = v & 3;
        const float* Wp = rel == 0 ? W0 : rel == 1 ? W1 : rel == 2 ? W2 : W3;
        const float* vec;
        if (v < 4) vec = rel == 0 ? al0 : rel == 1 ? al1 : rel == 2 ? al2 : al3;
        else vec = rel == 0 ? ar0 : rel == 1 ? ar1 : rel == 2 ? ar2 : ar3;
        int wave = tid >> 6, lane = tid & 63;
#pragma unroll 1
        for (int i = 0; i < 16; i++) {
            int k = kg * 64 + wave * 16 + i;
            float s = 0.f;
#pragma unroll
            for (int c = 0; c < 8; c++) s += Wp[(size_t)k * 512 + c * 64 + lane] * vec[c * 64 + lane];
#pragma unroll
            for (int off = 32; off > 0; off >>= 1) s += __shfl_xor(s, off);
            if (lane == 0) wal8[v * 512 + k] = s;
        }
    }
}

// ---------------- 6x 512x512 transpose + convert to bf16, one launch ----------------
__global__ __launch_bounds__(1024)
void k_transpose6(const float* __restrict__ W0, const float* __restrict__ W1,
                  const float* __restrict__ W2, const float* __restrict__ W3,
                  const float* __restrict__ Wl, __hip_bfloat16* __restrict__ Bt_all,
                  __hip_bfloat16* __restrict__ WlTb) {
    __shared__ float tile[32][33];
    int z = blockIdx.z;
    const float* in = z == 0 ? W0 : z == 1 ? W1 : z == 2 ? W2 : z == 3 ? W3
                      : (z == 4 ? Wl : Wl + (size_t)DD * DD);
    __hip_bfloat16* out = z < 5 ? Bt_all + (size_t)z * DD * DD : WlTb;
    int bx = blockIdx.x * 32;
    int by = blockIdx.y * 32;
    int tx = threadIdx.x, ty = threadIdx.y;
    tile[ty][tx] = in[(by + ty) * 512 + bx + tx];
    __syncthreads();
    out[(bx + ty) * 512 + by + tx] = __float2bfloat16(tile[tx][ty]);
}

// ---------------- el/er for all 4 relations from x (wal8 algebra) ----------------
__global__ __launch_bounds__(256)
void k_elr8(const __hip_bfloat16* __restrict__ x_bf, const float* __restrict__ wal8,
            float* __restrict__ el4, float* __restrict__ er4) {
    int wave = threadIdx.x >> 6, lane = threadIdx.x & 63;
    int r = blockIdx.x * 4 + wave;
    uint4 xv = *(const uint4*)(x_bf + (size_t)r * DD + lane * 8);
    const unsigned short* xs = (const unsigned short*)&xv;
    float xf[8];
#pragma unroll
    for (int j = 0; j < 8; j++) xf[j] = bfbits2f(xs[j]);
    float s[8];
#pragma unroll
    for (int v = 0; v < 8; v++) {
        const float* wp = wal8 + v * 512 + lane * 8;
        s[v] = xf[0] * wp[0] + xf[1] * wp[1] + xf[2] * wp[2] + xf[3] * wp[3] +
               xf[4] * wp[4] + xf[5] * wp[5] + xf[6] * wp[6] + xf[7] * wp[7];
    }
#pragma unroll
    for (int off = 32; off > 0; off >>= 1)
#pragma unroll
        for (int v = 0; v < 8; v++) s[v] += __shfl_xor(s[v], off);
    if (lane == 0) {
#pragma unroll
        for (int rel = 0; rel < 4; rel++) {
            el4[rel * NN + r] = s[rel];
            er4[rel * NN + r] = s[4 + rel];
        }
    }
}

// ---------------- GEMM (chain): 128x128, BK=64, R3 schedule + COALESCED staging ----
// R9-verified WIN (total -53us vs R8). R15 A/B: dbuf 2-phase at 128^2 = +62us
// regression (occupancy loss > latency hiding; confirmed twice, R4+R15). This
// single-buffer coalesced version is the keeper.
// mode 1: t_next = bf16(relu(C + xwl) + gnext)   (chain mid)
// mode 2: outf = relu(C + xwl) fp32              (chain last)
__global__ __launch_bounds__(512)
void k_gemm512(const __hip_bfloat16* __restrict__ A, const __hip_bfloat16* __restrict__ Bt,
               __hip_bfloat16* __restrict__ Cb, const __hip_bfloat16* __restrict__ xwl,
               const __hip_bfloat16* __restrict__ gnext, __hip_bfloat16* __restrict__ t_next,
               float* __restrict__ outf, int c_ld, int M, int CT, int mode) {
    const int RT = (M + 127) >> 7;
    const int xcd = blockIdx.x & 7;
    const int k_ = blockIdx.x >> 3;
    const int ctile = k_ % CT;
    const int rtile = (k_ / CT) * 8 + xcd;
    if (rtile >= RT) return;

    __shared__ __hip_bfloat16 As[128 * 64];  // 16 KB; row-major [128][64], chunks XOR-swz
    __shared__ __hip_bfloat16 Bs[128 * 64];  // 16 KB
    const int tid = threadIdx.x;
    const int lane = tid & 63;
    const int wave = tid >> 6;
    const int row0 = rtile * 128;
    const int col0 = ctile * 128;
    const int wm = (wave >> 2) * 64;   // 0 or 64
    const int wn = (wave & 3) * 32;    // 0,32,64,96
    const int q8 = lane >> 4;
    const int l15 = lane & 15;
    const int l7 = l15 & 7;

    // coalesced staging: wave w instr j stages 8 rows (w*16 + j*8 + rsub)
    const int rsub = lane >> 3;                // row within 8-row group
    const int csw = (lane & 7) ^ rsub;         // XOR-swizzled source chunk (involution)
    const __hip_bfloat16* aBase = A + (size_t)csw * 8;
    const __hip_bfloat16* bBase = Bt + (size_t)csw * 8;

    floatx4 acc[4][2];
#pragma unroll
    for (int a = 0; a < 4; a++)
#pragma unroll
        for (int b = 0; b < 2; b++) acc[a][b] = (floatx4){0.f, 0.f, 0.f, 0.f};

    for (int k0 = 0; k0 < DD; k0 += 64) {
        __syncthreads();
#pragma unroll
        for (int j = 0; j < 2; j++) {
            int arow = row0 + wave * 16 + j * 8 + rsub;
            if (arow >= M) arow = M - 1;
            int brow = col0 + wave * 16 + j * 8 + rsub;
            GLOAD_LDS16(aBase + (size_t)arow * DD + k0,
                        As + ((wave * 16 + j * 8) * 64) + (size_t)lane * 8);
            GLOAD_LDS16(bBase + (size_t)brow * DD + k0,
                        Bs + ((wave * 16 + j * 8) * 64) + (size_t)lane * 8);
        }
        __syncthreads();
#pragma unroll
        for (int kk = 0; kk < 2; kk++) {
            const int cp = ((kk * 4 + q8) ^ l7) * 8;
            short8 af[4], bf[2];
#pragma unroll
            for (int mi = 0; mi < 4; mi++)
                af[mi] = *(const short8*)(As + (size_t)(wm + mi * 16 + l15) * 64 + cp);
#pragma unroll
            for (int ni = 0; ni < 2; ni++)
                bf[ni] = *(const short8*)(Bs + (size_t)(wn + ni * 16 + l15) * 64 + cp);
#pragma unroll
            for (int mi = 0; mi < 4; mi++)
#pragma unroll
                for (int ni = 0; ni < 2; ni++)
                    acc[mi][ni] = __builtin_amdgcn_mfma_f32_16x16x32_bf16(af[mi], bf[ni],
                                                                          acc[mi][ni], 0, 0, 0);
        }
    }

#pragma unroll
    for (int mi = 0; mi < 4; mi++)
#pragma unroll
        for (int ni = 0; ni < 2; ni++)
#pragma unroll
            for (int r = 0; r < 4; r++) {
                int grow = row0 + wm + mi * 16 + q8 * 4 + r;
                int gcol = col0 + wn + ni * 16 + l15;
                if (grow < M) {
                    float v = acc[mi][ni][r];
                    if (mode == 0) {
                        Cb[(size_t)grow * c_ld + gcol] = __float2bfloat16(v);
                    } else {
                        v += bfbits2f(
                            *(const unsigned short*)(xwl + (size_t)grow * NH + 2048 + gcol));
                        v = v > 0.f ? v : 0.f;
                        size_t idx = (size_t)grow * DD + gcol;
                        if (mode == 1) {
                            v += bfbits2f(*(const unsigned short*)(gnext + idx));
                            t_next[idx] = __float2bfloat16(v);
                        } else {
                            outf[idx] = v;
                        }
                    }
                }
            }
}

// ---------------- MEGA-GEMM: 256x256, BK=64, dbuf 2-phase, COALESCED+SWIZZLED ------
// R8 WIN: 160->97us, MfmaUtil 13->22, conflicts 0. FROZEN.
__global__ __launch_bounds__(512)
void k_gemm256(const __hip_bfloat16* __restrict__ A, const __hip_bfloat16* __restrict__ Bt,
               __hip_bfloat16* __restrict__ Cb, int c_ld, int M, int CT) {
    const int RT = (M + 255) >> 8;
    const int xcd = blockIdx.x & 7;
    const int k_ = blockIdx.x >> 3;
    const int ctile = k_ % CT;
    const int rtile = (k_ / CT) * 8 + xcd;
    if (rtile >= RT) return;

    __shared__ __hip_bfloat16 As0[256 * 64];  // 32 KB each; row-major [row][64], chunks XOR-swz
    __shared__ __hip_bfloat16 Bs0[256 * 64];
    __shared__ __hip_bfloat16 As1[256 * 64];
    __shared__ __hip_bfloat16 Bs1[256 * 64];
    const int tid = threadIdx.x;
    const int lane = tid & 63;
    const int wave = tid >> 6;
    const int row0 = rtile * 256;
    const int col0 = ctile * 256;
    const int wm = (wave >> 2) * 128;  // 0 or 128
    const int wn = (wave & 3) * 64;    // 0,64,128,192
    const int q8 = lane >> 4;
    const int l15 = lane & 15;
    const int l7 = l15 & 7;

    // staging: wave w, instr j stages 8 rows (w*32 + j*8 + rsub), lane reads chunk csw
    const int rsub = lane >> 3;                // row within 8-row group
    const int csw = (lane & 7) ^ rsub;         // XOR-swizzled source chunk (involution)
    const __hip_bfloat16* aBase = A + (size_t)csw * 8;
    const __hip_bfloat16* bBase = Bt + (size_t)csw * 8;

#define STAGE256(k0, AL, BL)                                                              \
    {                                                                                     \
        _Pragma("unroll") for (int j = 0; j < 4; j++) {                                   \
            int arow = row0 + wave * 32 + j * 8 + rsub;                                   \
            if (arow >= M) arow = M - 1;                                                  \
            int brow = col0 + wave * 32 + j * 8 + rsub;                                   \
            GLOAD_LDS16(aBase + (size_t)arow * DD + (k0),                                 \
                        (AL) + ((wave * 32 + j * 8) * 64) + (size_t)lane * 8);            \
            GLOAD_LDS16(bBase + (size_t)brow * DD + (k0),                                 \
                        (BL) + ((wave * 32 + j * 8) * 64) + (size_t)lane * 8);            \
        }                                                                                 \
    }

#define COMPUTE256(AS, BS)                                                          \
    {                                                                               \
        _Pragma("unroll") for (int kk = 0; kk < 2; kk++) {                          \
            const int cp = ((kk * 4 + q8) ^ l7) * 8;                                \
            short8 af[8], bfr[4];                                                   \
            _Pragma("unroll") for (int mi = 0; mi < 8; mi++)                        \
                af[mi] = *(const short8*)((AS) +                                    \
                    (size_t)(wm + mi * 16 + l15) * 64 + cp);                        \
            _Pragma("unroll") for (int ni = 0; ni < 4; ni++)                        \
                bfr[ni] = *(const short8*)((BS) +                                   \
                    (size_t)(wn + ni * 16 + l15) * 64 + cp);                        \
            _Pragma("unroll") for (int mi = 0; mi < 8; mi++)                        \
                _Pragma("unroll") for (int ni = 0; ni < 4; ni++)                    \
                    acc[mi][ni] = __builtin_amdgcn_mfma_f32_16x16x32_bf16(          \
                        af[mi], bfr[ni], acc[mi][ni], 0, 0, 0);                     \
        }                                                                           \
    }

    floatx4 acc[8][4];
#pragma unroll
    for (int a = 0; a < 8; a++)
#pragma unroll
        for (int b = 0; b < 4; b++) acc[a][b] = (floatx4){0.f, 0.f, 0.f, 0.f};

    // prologue: stage K-tile 0 into buf0; syncthreads drains vmcnt + barriers
    STAGE256(0, As0, Bs0)
    __syncthreads();

    // 8 K-tiles (DD=512, BK=64), 2 per iteration; stage t+1 BEFORE computing t
#pragma unroll 1
    for (int t0 = 0; t0 < 8; t0 += 2) {
        STAGE256(t0 * 64 + 64, As1, Bs1)       // tile t0+1 -> buf1 (always exists)
        COMPUTE256(As0, Bs0)                   // tile t0 from buf0
        __syncthreads();                       // vmcnt(0): t0+1 loads landed under compute
        if (t0 < 6) STAGE256(t0 * 64 + 128, As0, Bs0)  // tile t0+2 -> buf0
        COMPUTE256(As1, Bs1)                   // tile t0+1 from buf1
        __syncthreads();
    }
#undef STAGE256
#undef COMPUTE256

#pragma unroll
    for (int mi = 0; mi < 8; mi++)
#pragma unroll
        for (int ni = 0; ni < 4; ni++)
#pragma unroll
            for (int r = 0; r < 4; r++) {
                int grow = row0 + wm + mi * 16 + q8 * 4 + r;
                int gcol = col0 + wn + ni * 16 + l15;
                if (grow < M) Cb[(size_t)grow * c_ld + gcol] = __float2bfloat16(acc[mi][ni][r]);
            }
}

// ---------------- CSR build (batched over 4 relations) ----------------
__global__ void k_count4(const int* __restrict__ e0, const int* __restrict__ e1,
                         const int* __restrict__ e2, const int* __restrict__ e3,
                         int* __restrict__ deg4) {
    int g = blockIdx.x * blockDim.x + threadIdx.x;
    if (g >= 4 * EE) return;
    int rel = g / EE;
    int e = g - rel * EE;
    const int* ed = rel == 0 ? e0 : rel == 1 ? e1 : rel == 2 ? e2 : e3;
    atomicAdd(&deg4[rel * NN + ed[EE + e]], 1);
}

__global__ __launch_bounds__(1024)
void k_scan4(const int* __restrict__ deg4, int* __restrict__ rp4, int* __restrict__ cur4) {
    const int rel = blockIdx.x;
    const int* deg = deg4 + rel * NN;
    int* row_ptr = rp4 + rel * (NN + 1);
    int* cursor = cur4 + rel * NN;
    __shared__ int sm[1024];
    int t = threadIdx.x;
    const int CH = 20;
    int begin = t * CH;
    int end = begin + CH;
    if (end > NN) end = NN;
    int s = 0;
    if (begin < NN)
        for (int i = begin; i < end; i++) s += deg[i];
    sm[t] = s;
    __syncthreads();
    for (int off = 1; off < 1024; off <<= 1) {
        int v = (t >= off) ? sm[t - off] : 0;
        __syncthreads();
        sm[t] += v;
        __syncthreads();
    }
    int run = sm[t] - s;
    if (begin < NN) {
        for (int i = begin; i < end; i++) {
            row_ptr[i] = run;
            cursor[i] = run;
            run += deg[i];
        }
        if (end == NN) row_ptr[NN] = run;
    }
}

__global__ void k_scatter4(const int* __restrict__ e0, const int* __restrict__ e1,
                           const int* __restrict__ e2, const int* __restrict__ e3,
                           int* __restrict__ cur4, int* __restrict__ csr4) {
    int g = blockIdx.x * blockDim.x + threadIdx.x;
    if (g >= 4 * EE) return;
    int rel = g / EE;
    int e = g - rel * EE;
    const int* ed = rel == 0 ? e0 : rel == 1 ? e1 : rel == 2 ? e2 : e3;
    int dst = ed[EE + e];
    int pos = atomicAdd(&cur4[rel * NN + dst], 1);
    csr4[rel * EE + pos] = ed[e];
}

// ---------------- BATCHED edge-softmax + aggregate (+bias), wave per dst ----------
// R9 version (86.6us, occupancy 74%): at the random-gather BW floor (~4 TB/s);
// R10 (readlane pipeline) and R11 confirmed ILP restructures are net-negative.
__global__ __launch_bounds__(256)
void k_agg4(const int* __restrict__ rp4, const int* __restrict__ csr4,
            const float* __restrict__ el4, const float* __restrict__ er4,
            const __hip_bfloat16* __restrict__ h_all, const float* __restrict__ bias,
            __hip_bfloat16* __restrict__ gat4, float* __restrict__ alpha4) {
    const int rel = blockIdx.y;
    const int* row_ptr = rp4 + rel * (NN + 1);
    const int* csr_src = csr4 + (size_t)rel * EE;
    const float* el = el4 + rel * NN;
    const float* er = er4 + rel * NN;
    const __hip_bfloat16* h = h_all + (size_t)rel * 512;
    float* alpha_tmp = alpha4 + (size_t)rel * EE;

    int d = (blockIdx.x * blockDim.x + threadIdx.x) >> 6;
    int lane = threadIdx.x & 63;
    if (d >= NN) return;
    int s0 = row_ptr[d], s1 = row_ptr[d + 1];
    int deg = s1 - s0;
    int base = lane * 8;
    float acc[8] = {0.f, 0.f, 0.f, 0.f, 0.f, 0.f, 0.f, 0.f};

    if (deg <= 64) {
        int sv = 0;
        float av = 0.f;
        if (lane < deg) sv = csr_src[s0 + lane];
        float erd = er[d];
        float v = -1e30f;
        if (lane < deg) {
            float e = el[sv] + erd;
            v = e >= 0.f ? e : 0.2f * e;
        }
        float m = v;
#pragma unroll
        for (int off = 32; off > 0; off >>= 1) m = fmaxf(m, __shfl_xor(m, off));
        float wgt = (lane < deg) ? __expf(v - m) : 0.f;
        float s = wgt;
#pragma unroll
        for (int off = 32; off > 0; off >>= 1) s += __shfl_xor(s, off);
        av = wgt / s;
        int t = 0;
        for (; t + 3 < deg; t += 4) {
            int sA = __shfl(sv, t), sB = __shfl(sv, t + 1);
            int sC = __shfl(sv, t + 2), sD = __shfl(sv, t + 3);
            float aA = __shfl(av, t), aB = __shfl(av, t + 1);
            float aC = __shfl(av, t + 2), aD = __shfl(av, t + 3);
            uint4 hv0 = *(const uint4*)(h + (size_t)sA * NH + base);
            uint4 hv1 = *(const uint4*)(h + (size_t)sB * NH + base);
            uint4 hv2 = *(const uint4*)(h + (size_t)sC * NH + base);
            uint4 hv3 = *(const uint4*)(h + (size_t)sD * NH + base);
            const unsigned short* h0 = (const unsigned short*)&hv0;
            const unsigned short* h1 = (const unsigned short*)&hv1;
            const unsigned short* h2 = (const unsigned short*)&hv2;
            const unsigned short* h3 = (const unsigned short*)&hv3;
#pragma unroll
            for (int k = 0; k < 8; k++)
                acc[k] += aA * bfbits2f(h0[k]) + aB * bfbits2f(h1[k]) + aC * bfbits2f(h2[k]) +
                          aD * bfbits2f(h3[k]);
        }
        for (; t < deg; t++) {
            int sA = __shfl(sv, t);
            float aA = __shfl(av, t);
            uint4 hv0 = *(const uint4*)(h + (size_t)sA * NH + base);
            const unsigned short* h0 = (const unsigned short*)&hv0;
#pragma unroll
            for (int k = 0; k < 8; k++) acc[k] += aA * bfbits2f(h0[k]);
        }
    } else {
        float erd = er[d];
        float m = -1e30f;
        for (int j = s0 + lane; j < s1; j += 64) {
            float e = el[csr_src[j]] + erd;
            e = e >= 0.f ? e : 0.2f * e;
            alpha_tmp[j] = e;
            m = fmaxf(m, e);
        }
#pragma unroll
        for (int off = 32; off > 0; off >>= 1) m = fmaxf(m, __shfl_xor(m, off));
        float s = 0.f;
        for (int j = s0 + lane; j < s1; j += 64) {
            float wv = __expf(alpha_tmp[j] - m);
            alpha_tmp[j] = wv;
            s += wv;
        }
#pragma unroll
        for (int off = 32; off > 0; off >>= 1) s += __shfl_xor(s, off);
        float inv = 1.f / s;
        for (int j0 = 0; j0 < deg; j0 += 64) {
            int cnt = deg - j0;
            if (cnt > 64) cnt = 64;
            int sv = 0;
            float av = 0.f;
            if (lane < cnt) {
                sv = csr_src[s0 + j0 + lane];
                av = alpha_tmp[s0 + j0 + lane] * inv;
            }
            for (int t = 0; t < cnt; t++) {
                int sA = __shfl(sv, t);
                float aA = __shfl(av, t);
                uint4 hv0 = *(const uint4*)(h + (size_t)sA * NH + base);
                const unsigned short* h0 = (const unsigned short*)&hv0;
#pragma unroll
                for (int k = 0; k < 8; k++) acc[k] += aA * bfbits2f(h0[k]);
            }
        }
    }

    float4 b0 = *(const float4*)(bias + base);
    float4 b1 = *(const float4*)(bias + base + 4);
    acc[0] += b0.x; acc[1] += b0.y; acc[2] += b0.z; acc[3] += b0.w;
    acc[4] += b1.x; acc[5] += b1.y; acc[6] += b1.z; acc[7] += b1.w;
    union { __hip_bfloat16 b[8]; uint4 u; } cv;
#pragma unroll
    for (int k = 0; k < 8; k++) cv.b[k] = __float2bfloat16(acc[k]);
    *(uint4*)(gat4 + (size_t)rel * NN * DD + (size_t)d * DD + base) = cv.u;
}

extern "C" void kernel_launch(void* const* d_in, const int* in_sizes, int n_in,
                              void* d_out, int out_size, void* d_ws, size_t ws_size,
                              hipStream_t stream) {
    const float* x = (const float*)d_in[0];
    const int* edges[4] = {(const int*)d_in[1], (const int*)d_in[5], (const int*)d_in[9],
                           (const int*)d_in[13]};
    const float* W[4] = {(const float*)d_in[2], (const float*)d_in[6], (const float*)d_in[10],
                         (const float*)d_in[14]};
    const float* al[4] = {(const float*)d_in[3], (const float*)d_in[7], (const float*)d_in[11],
                          (const float*)d_in[15]};
    const float* ar[4] = {(const float*)d_in[4], (const float*)d_in[8], (const float*)d_in[12],
                          (const float*)d_in[16]};
    const float* Wl = (const float*)d_in[17];
    const float* bias = (const float*)d_in[18];
    float* out = (float*)d_out;

    char* w = (char*)d_ws;
    auto alloc = [&](size_t bytes) {
        char* p = w;
        w += (bytes + 255) & ~(size_t)255;
        return p;
    };
    __hip_bfloat16* x_bf = (__hip_bfloat16*)alloc((size_t)NN * DD * 2);
    __hip_bfloat16* h_all = (__hip_bfloat16*)alloc((size_t)NN * NH * 2);   // [h0..h3|xwl]
    __hip_bfloat16* gat4 = (__hip_bfloat16*)alloc((size_t)4 * NN * DD * 2);
    __hip_bfloat16* t_A = (__hip_bfloat16*)alloc((size_t)NN * DD * 2);
    __hip_bfloat16* t_B = (__hip_bfloat16*)alloc((size_t)NN * DD * 2);
    __hip_bfloat16* Bt_all = (__hip_bfloat16*)alloc((size_t)NH * DD * 2);  // [W0..W3,WlTop]^T
    __hip_bfloat16* WlTb = (__hip_bfloat16*)alloc((size_t)DD * DD * 2);
    float* wal8 = (float*)alloc((size_t)8 * 512 * 4);
    float* el4 = (float*)alloc((size_t)4 * NN * 4);
    float* er4 = (float*)alloc((size_t)4 * NN * 4);
    int* deg4 = (int*)alloc((size_t)4 * NN * 4);
    int* rp4 = (int*)alloc((size_t)4 * (NN + 1) * 4);
    int* cur4 = (int*)alloc((size_t)4 * NN * 4);
    int* csr4 = (int*)alloc((size_t)4 * EE * 4);
    float* alpha4 = (float*)alloc((size_t)4 * EE * 4);

    // fused preprocessing: convert x, zero deg4, wal8 = W@al / W@ar
    k_preproc<<<PRE_CONV + PRE_ZERO + PRE_WAL, 256, 0, stream>>>(
        x, x_bf, deg4, W[0], W[1], W[2], W[3], al[0], al[1], al[2], al[3], ar[0], ar[1], ar[2],
        ar[3], wal8);
    dim3 tb(32, 32), tg6(16, 16, 6);
    k_transpose6<<<tg6, tb, 0, stream>>>(W[0], W[1], W[2], W[3], Wl, Bt_all, WlTb);

    // CSR for all 4 relations
    k_count4<<<(4 * EE + 255) / 256, 256, 0, stream>>>(edges[0], edges[1], edges[2], edges[3], deg4);
    k_scan4<<<4, 1024, 0, stream>>>(deg4, rp4, cur4);
    k_scatter4<<<(4 * EE + 255) / 256, 256, 0, stream>>>(edges[0], edges[1], edges[2], edges[3],
                                                         cur4, csr4);

    // el/er from x directly
    k_elr8<<<NN / 4, 256, 0, stream>>>(x_bf, wal8, el4, er4);

    // MEGA-GEMM: h_all = x @ [W0..W3|Wl_top], 256x256 tiles, CT=10, coalesced staging
    const int RT256p8 = (((NN + 255) / 256 + 7) / 8) * 8;  // 80
    k_gemm256<<<RT256p8 * 10, 512, 0, stream>>>(x_bf, Bt_all, h_all, NH, NN, 10);

    // batched aggregate (+bias), wave per dst
    dim3 gagg((NN * 64 + 255) / 256, 4);
    k_agg4<<<gagg, 256, 0, stream>>>(rp4, csr4, el4, er4, h_all, bias, gat4, alpha4);

    // serial chain: t_{i+1} = relu(t_i @ Wl_bot + xwl) + gat4[i+1]; last writes fp32 out
    const int RT128p8 = (((NN + 127) / 128 + 7) / 8) * 8;  // 160
    const int NB = RT128p8 * 4;
    k_gemm512<<<NB, 512, 0, stream>>>(gat4, WlTb, nullptr, h_all, gat4 + (size_t)1 * NN * DD, t_A,
                                      nullptr, DD, NN, 4, 1);
    k_gemm512<<<NB, 512, 0, stream>>>(t_A, WlTb, nullptr, h_all, gat4 + (size_t)2 * NN * DD, t_B,
                                      nullptr, DD, NN, 4, 1);
    k_gemm512<<<NB, 512, 0, stream>>>(t_B, WlTb, nullptr, h_all, gat4 + (size_t)3 * NN * DD, t_A,
                                      nullptr, DD, NN, 4, 1);
    k_gemm512<<<NB, 512, 0, stream>>>(t_A, WlTb, nullptr, h_all, nullptr, nullptr, out, DD, NN, 4,
                                      2);
}

// Round 17
// 520.765 us; speedup vs baseline: 1.1490x; 1.0250x over previous
//
#include <hip/hip_runtime.h>
#include <hip/hip_bf16.h>

#define NN 20000
#define DD 512
#define EE 150000
#define NH 2560  // stacked GEMM width: 4*512 (W_i) + 512 (Wl_top)

typedef __attribute__((ext_vector_type(8))) short short8;
typedef __attribute__((ext_vector_type(4))) float floatx4;

static __device__ __forceinline__ float bfbits2f(unsigned short u) {
    unsigned int x = ((unsigned int)u) << 16;
    return __uint_as_float(x);
}

#define GLOAD_LDS16(g, l)                                                        \
    __builtin_amdgcn_global_load_lds((const __attribute__((address_space(1))) void*)(g), \
                                     (__attribute__((address_space(3))) void*)(l), 16, 0, 0)

// ------- fused L1: convert x, zero deg4, wal8, 6x transpose (R16: launch fusion) ---
#define PRE_CONV 10000
#define PRE_ZERO 313
#define PRE_WAL 64
#define PRE_TR 1536  // 6 mats x 16x16 tiles
__global__ __launch_bounds__(256)
void k_fused_pre(const float* __restrict__ x, __hip_bfloat16* __restrict__ x_bf,
                 int* __restrict__ deg4,
                 const float* __restrict__ W0, const float* __restrict__ W1,
                 const float* __restrict__ W2, const float* __restrict__ W3,
                 const float* __restrict__ al0, const float* __restrict__ al1,
                 const float* __restrict__ al2, const float* __restrict__ al3,
                 const float* __restrict__ ar0, const float* __restrict__ ar1,
                 const float* __restrict__ ar2, const float* __restrict__ ar3,
                 float* __restrict__ wal8, const float* __restrict__ Wl,
                 __hip_bfloat16* __restrict__ Bt_all, __hip_bfloat16* __restrict__ WlTb) {
    int b = blockIdx.x;
    int tid = threadIdx.x;
    if (b < PRE_CONV) {
        int i = b * 256 + tid;
        float4 v = ((const float4*)x)[i];
        union { __hip_bfloat16 bb[4]; ushort4 u; } cv;
        cv.bb[0] = __float2bfloat16(v.x);
        cv.bb[1] = __float2bfloat16(v.y);
        cv.bb[2] = __float2bfloat16(v.z);
        cv.bb[3] = __float2bfloat16(v.w);
        *(ushort4*)(x_bf + 4l * i) = cv.u;
    } else if (b < PRE_CONV + PRE_ZERO) {
        int i = (b - PRE_CONV) * 256 + tid;
        if (i < 4 * NN) deg4[i] = 0;
    } else if (b < PRE_CONV + PRE_ZERO + PRE_WAL) {
        int vk = b - PRE_CONV - PRE_ZERO;
        int v = vk >> 3, kg = vk & 7;
        int rel = v & 3;
        const float* Wp = rel == 0 ? W0 : rel == 1 ? W1 : rel == 2 ? W2 : W3;
        const float* vec;
        if (v < 4) vec = rel == 0 ? al0 : rel == 1 ? al1 : rel == 2 ? al2 : al3;
        else vec = rel == 0 ? ar0 : rel == 1 ? ar1 : rel == 2 ? ar2 : ar3;
        int wave = tid >> 6, lane = tid & 63;
#pragma unroll 1
        for (int i = 0; i < 16; i++) {
            int k = kg * 64 + wave * 16 + i;
            float s = 0.f;
#pragma unroll
            for (int c = 0; c < 8; c++) s += Wp[(size_t)k * 512 + c * 64 + lane] * vec[c * 64 + lane];
#pragma unroll
            for (int off = 32; off > 0; off >>= 1) s += __shfl_xor(s, off);
            if (lane == 0) wal8[v * 512 + k] = s;
        }
    } else {
        // transpose6 re-expressed at 256 threads: 4 rows/thread
        int t = b - PRE_CONV - PRE_ZERO - PRE_WAL;
        int z = t >> 8;            // /256
        int rem = t & 255;
        int by = (rem >> 4) * 32;  // /16
        int bx = (rem & 15) * 32;
        const float* in = z == 0 ? W0 : z == 1 ? W1 : z == 2 ? W2 : z == 3 ? W3
                          : (z == 4 ? Wl : Wl + (size_t)DD * DD);
        __hip_bfloat16* out = z < 5 ? Bt_all + (size_t)z * DD * DD : WlTb;
        __shared__ float tile[32][33];
        int tx = tid & 31, ty0 = tid >> 5;  // ty0 in 0..7
#pragma unroll
        for (int r = 0; r < 4; r++) {
            int row = ty0 + r * 8;
            tile[row][tx] = in[(size_t)(by + row) * 512 + bx + tx];
        }
        __syncthreads();
#pragma unroll
        for (int r = 0; r < 4; r++) {
            int row = ty0 + r * 8;
            out[(size_t)(bx + row) * 512 + by + tx] = __float2bfloat16(tile[tx][row]);
        }
    }
}

// ------- fused L2: count4 + elr8 (both depend only on L1 outputs) ------------------
#define MID_CNT 2344  // ceil(4*EE/256)
__global__ __launch_bounds__(256)
void k_fused_mid(const int* __restrict__ e0, const int* __restrict__ e1,
                 const int* __restrict__ e2, const int* __restrict__ e3,
                 int* __restrict__ deg4, const __hip_bfloat16* __restrict__ x_bf,
                 const float* __restrict__ wal8, float* __restrict__ el4,
                 float* __restrict__ er4) {
    int b = blockIdx.x;
    int tid = threadIdx.x;
    if (b < MID_CNT) {
        int g = b * 256 + tid;
        if (g >= 4 * EE) return;
        int rel = g / EE;
        int e = g - rel * EE;
        const int* ed = rel == 0 ? e0 : rel == 1 ? e1 : rel == 2 ? e2 : e3;
        atomicAdd(&deg4[rel * NN + ed[EE + e]], 1);
        return;
    }
    int wave = tid >> 6, lane = tid & 63;
    int r = (b - MID_CNT) * 4 + wave;
    uint4 xv = *(const uint4*)(x_bf + (size_t)r * DD + lane * 8);
    const unsigned short* xs = (const unsigned short*)&xv;
    float xf[8];
#pragma unroll
    for (int j = 0; j < 8; j++) xf[j] = bfbits2f(xs[j]);
    float s[8];
#pragma unroll
    for (int v = 0; v < 8; v++) {
        const float* wp = wal8 + v * 512 + lane * 8;
        s[v] = xf[0] * wp[0] + xf[1] * wp[1] + xf[2] * wp[2] + xf[3] * wp[3] +
               xf[4] * wp[4] + xf[5] * wp[5] + xf[6] * wp[6] + xf[7] * wp[7];
    }
#pragma unroll
    for (int off = 32; off > 0; off >>= 1)
#pragma unroll
        for (int v = 0; v < 8; v++) s[v] += __shfl_xor(s[v], off);
    if (lane == 0) {
#pragma unroll
        for (int rel = 0; rel < 4; rel++) {
            el4[rel * NN + r] = s[rel];
            er4[rel * NN + r] = s[4 + rel];
        }
    }
}

// ---------------- GEMM (chain): 128x128, BK=64, R3 schedule + COALESCED staging ----
// R9-verified WIN. R15 A/B: dbuf at 128^2 = +62us regression. Single-buffer keeper.
// mode 1: t_next = bf16(relu(C + xwl) + gnext)   (chain mid)
// mode 2: outf = relu(C + xwl) fp32              (chain last)
__global__ __launch_bounds__(512)
void k_gemm512(const __hip_bfloat16* __restrict__ A, const __hip_bfloat16* __restrict__ Bt,
               __hip_bfloat16* __restrict__ Cb, const __hip_bfloat16* __restrict__ xwl,
               const __hip_bfloat16* __restrict__ gnext, __hip_bfloat16* __restrict__ t_next,
               float* __restrict__ outf, int c_ld, int M, int CT, int mode) {
    const int RT = (M + 127) >> 7;
    const int xcd = blockIdx.x & 7;
    const int k_ = blockIdx.x >> 3;
    const int ctile = k_ % CT;
    const int rtile = (k_ / CT) * 8 + xcd;
    if (rtile >= RT) return;

    __shared__ __hip_bfloat16 As[128 * 64];  // 16 KB; row-major [128][64], chunks XOR-swz
    __shared__ __hip_bfloat16 Bs[128 * 64];  // 16 KB
    const int tid = threadIdx.x;
    const int lane = tid & 63;
    const int wave = tid >> 6;
    const int row0 = rtile * 128;
    const int col0 = ctile * 128;
    const int wm = (wave >> 2) * 64;   // 0 or 64
    const int wn = (wave & 3) * 32;    // 0,32,64,96
    const int q8 = lane >> 4;
    const int l15 = lane & 15;
    const int l7 = l15 & 7;

    const int rsub = lane >> 3;
    const int csw = (lane & 7) ^ rsub;
    const __hip_bfloat16* aBase = A + (size_t)csw * 8;
    const __hip_bfloat16* bBase = Bt + (size_t)csw * 8;

    floatx4 acc[4][2];
#pragma unroll
    for (int a = 0; a < 4; a++)
#pragma unroll
        for (int b = 0; b < 2; b++) acc[a][b] = (floatx4){0.f, 0.f, 0.f, 0.f};

    for (int k0 = 0; k0 < DD; k0 += 64) {
        __syncthreads();
#pragma unroll
        for (int j = 0; j < 2; j++) {
            int arow = row0 + wave * 16 + j * 8 + rsub;
            if (arow >= M) arow = M - 1;
            int brow = col0 + wave * 16 + j * 8 + rsub;
            GLOAD_LDS16(aBase + (size_t)arow * DD + k0,
                        As + ((wave * 16 + j * 8) * 64) + (size_t)lane * 8);
            GLOAD_LDS16(bBase + (size_t)brow * DD + k0,
                        Bs + ((wave * 16 + j * 8) * 64) + (size_t)lane * 8);
        }
        __syncthreads();
#pragma unroll
        for (int kk = 0; kk < 2; kk++) {
            const int cp = ((kk * 4 + q8) ^ l7) * 8;
            short8 af[4], bf[2];
#pragma unroll
            for (int mi = 0; mi < 4; mi++)
                af[mi] = *(const short8*)(As + (size_t)(wm + mi * 16 + l15) * 64 + cp);
#pragma unroll
            for (int ni = 0; ni < 2; ni++)
                bf[ni] = *(const short8*)(Bs + (size_t)(wn + ni * 16 + l15) * 64 + cp);
#pragma unroll
            for (int mi = 0; mi < 4; mi++)
#pragma unroll
                for (int ni = 0; ni < 2; ni++)
                    acc[mi][ni] = __builtin_amdgcn_mfma_f32_16x16x32_bf16(af[mi], bf[ni],
                                                                          acc[mi][ni], 0, 0, 0);
        }
    }

#pragma unroll
    for (int mi = 0; mi < 4; mi++)
#pragma unroll
        for (int ni = 0; ni < 2; ni++)
#pragma unroll
            for (int r = 0; r < 4; r++) {
                int grow = row0 + wm + mi * 16 + q8 * 4 + r;
                int gcol = col0 + wn + ni * 16 + l15;
                if (grow < M) {
                    float v = acc[mi][ni][r];
                    if (mode == 0) {
                        Cb[(size_t)grow * c_ld + gcol] = __float2bfloat16(v);
                    } else {
                        v += bfbits2f(
                            *(const unsigned short*)(xwl + (size_t)grow * NH + 2048 + gcol));
                        v = v > 0.f ? v : 0.f;
                        size_t idx = (size_t)grow * DD + gcol;
                        if (mode == 1) {
                            v += bfbits2f(*(const unsigned short*)(gnext + idx));
                            t_next[idx] = __float2bfloat16(v);
                        } else {
                            outf[idx] = v;
                        }
                    }
                }
            }
}

// ---------------- MEGA-GEMM: 256x256, BK=64, dbuf 2-phase, COALESCED+SWIZZLED ------
// R8 WIN (frozen). R16: absorbs scan4 into 4 tail blocks (800..803, 512thr CH=40).
#define GEMM256_BLKS 800
__global__ __launch_bounds__(512)
void k_gemm256(const __hip_bfloat16* __restrict__ A, const __hip_bfloat16* __restrict__ Bt,
               __hip_bfloat16* __restrict__ Cb, int c_ld, int M, int CT,
               const int* __restrict__ deg4, int* __restrict__ rp4, int* __restrict__ cur4) {
    if (blockIdx.x >= GEMM256_BLKS) {
        // scan4 @512 threads
        const int rel = blockIdx.x - GEMM256_BLKS;
        const int* deg = deg4 + rel * NN;
        int* row_ptr = rp4 + rel * (NN + 1);
        int* cursor = cur4 + rel * NN;
        __shared__ int sm[512];
        int t = threadIdx.x;
        const int CH = 40;
        int begin = t * CH;
        int end = begin + CH;
        if (end > NN) end = NN;
        int s = 0;
        if (begin < NN)
            for (int i = begin; i < end; i++) s += deg[i];
        sm[t] = s;
        __syncthreads();
        for (int off = 1; off < 512; off <<= 1) {
            int v = (t >= off) ? sm[t - off] : 0;
            __syncthreads();
            sm[t] += v;
            __syncthreads();
        }
        int run = sm[t] - s;
        if (begin < NN) {
            for (int i = begin; i < end; i++) {
                row_ptr[i] = run;
                cursor[i] = run;
                run += deg[i];
            }
            if (end == NN) row_ptr[NN] = run;
        }
        return;
    }
    const int RT = (M + 255) >> 8;
    const int xcd = blockIdx.x & 7;
    const int k_ = blockIdx.x >> 3;
    const int ctile = k_ % CT;
    const int rtile = (k_ / CT) * 8 + xcd;
    if (rtile >= RT) return;

    __shared__ __hip_bfloat16 As0[256 * 64];  // 32 KB each; row-major, chunks XOR-swz
    __shared__ __hip_bfloat16 Bs0[256 * 64];
    __shared__ __hip_bfloat16 As1[256 * 64];
    __shared__ __hip_bfloat16 Bs1[256 * 64];
    const int tid = threadIdx.x;
    const int lane = tid & 63;
    const int wave = tid >> 6;
    const int row0 = rtile * 256;
    const int col0 = ctile * 256;
    const int wm = (wave >> 2) * 128;  // 0 or 128
    const int wn = (wave & 3) * 64;    // 0,64,128,192
    const int q8 = lane >> 4;
    const int l15 = lane & 15;
    const int l7 = l15 & 7;

    const int rsub = lane >> 3;
    const int csw = (lane & 7) ^ rsub;
    const __hip_bfloat16* aBase = A + (size_t)csw * 8;
    const __hip_bfloat16* bBase = Bt + (size_t)csw * 8;

#define STAGE256(k0, AL, BL)                                                              \
    {                                                                                     \
        _Pragma("unroll") for (int j = 0; j < 4; j++) {                                   \
            int arow = row0 + wave * 32 + j * 8 + rsub;                                   \
            if (arow >= M) arow = M - 1;                                                  \
            int brow = col0 + wave * 32 + j * 8 + rsub;                                   \
            GLOAD_LDS16(aBase + (size_t)arow * DD + (k0),                                 \
                        (AL) + ((wave * 32 + j * 8) * 64) + (size_t)lane * 8);            \
            GLOAD_LDS16(bBase + (size_t)brow * DD + (k0),                                 \
                        (BL) + ((wave * 32 + j * 8) * 64) + (size_t)lane * 8);            \
        }                                                                                 \
    }

#define COMPUTE256(AS, BS)                                                          \
    {                                                                               \
        _Pragma("unroll") for (int kk = 0; kk < 2; kk++) {                          \
            const int cp = ((kk * 4 + q8) ^ l7) * 8;                                \
            short8 af[8], bfr[4];                                                   \
            _Pragma("unroll") for (int mi = 0; mi < 8; mi++)                        \
                af[mi] = *(const short8*)((AS) +                                    \
                    (size_t)(wm + mi * 16 + l15) * 64 + cp);                        \
            _Pragma("unroll") for (int ni = 0; ni < 4; ni++)                        \
                bfr[ni] = *(const short8*)((BS) +                                   \
                    (size_t)(wn + ni * 16 + l15) * 64 + cp);                        \
            _Pragma("unroll") for (int mi = 0; mi < 8; mi++)                        \
                _Pragma("unroll") for (int ni = 0; ni < 4; ni++)                    \
                    acc[mi][ni] = __builtin_amdgcn_mfma_f32_16x16x32_bf16(          \
                        af[mi], bfr[ni], acc[mi][ni], 0, 0, 0);                     \
        }                                                                           \
    }

    floatx4 acc[8][4];
#pragma unroll
    for (int a = 0; a < 8; a++)
#pragma unroll
        for (int b = 0; b < 4; b++) acc[a][b] = (floatx4){0.f, 0.f, 0.f, 0.f};

    STAGE256(0, As0, Bs0)
    __syncthreads();

#pragma unroll 1
    for (int t0 = 0; t0 < 8; t0 += 2) {
        STAGE256(t0 * 64 + 64, As1, Bs1)
        COMPUTE256(As0, Bs0)
        __syncthreads();
        if (t0 < 6) STAGE256(t0 * 64 + 128, As0, Bs0)
        COMPUTE256(As1, Bs1)
        __syncthreads();
    }
#undef STAGE256
#undef COMPUTE256

#pragma unroll
    for (int mi = 0; mi < 8; mi++)
#pragma unroll
        for (int ni = 0; ni < 4; ni++)
#pragma unroll
            for (int r = 0; r < 4; r++) {
                int grow = row0 + wm + mi * 16 + q8 * 4 + r;
                int gcol = col0 + wn + ni * 16 + l15;
                if (grow < M) Cb[(size_t)grow * c_ld + gcol] = __float2bfloat16(acc[mi][ni][r]);
            }
}

// ---------------- scatter (batched over 4 relations) ----------------
__global__ void k_scatter4(const int* __restrict__ e0, const int* __restrict__ e1,
                           const int* __restrict__ e2, const int* __restrict__ e3,
                           int* __restrict__ cur4, int* __restrict__ csr4) {
    int g = blockIdx.x * blockDim.x + threadIdx.x;
    if (g >= 4 * EE) return;
    int rel = g / EE;
    int e = g - rel * EE;
    const int* ed = rel == 0 ? e0 : rel == 1 ? e1 : rel == 2 ? e2 : e3;
    int dst = ed[EE + e];
    int pos = atomicAdd(&cur4[rel * NN + dst], 1);
    csr4[rel * EE + pos] = ed[e];
}

// ---------------- BATCHED edge-softmax + aggregate (+bias), wave per dst ----------
// R9 version (86.6us, occupancy 74%): at the random-gather BW floor (~4 TB/s).
__global__ __launch_bounds__(256)
void k_agg4(const int* __restrict__ rp4, const int* __restrict__ csr4,
            const float* __restrict__ el4, const float* __restrict__ er4,
            const __hip_bfloat16* __restrict__ h_all, const float* __restrict__ bias,
            __hip_bfloat16* __restrict__ gat4, float* __restrict__ alpha4) {
    const int rel = blockIdx.y;
    const int* row_ptr = rp4 + rel * (NN + 1);
    const int* csr_src = csr4 + (size_t)rel * EE;
    const float* el = el4 + rel * NN;
    const float* er = er4 + rel * NN;
    const __hip_bfloat16* h = h_all + (size_t)rel * 512;
    float* alpha_tmp = alpha4 + (size_t)rel * EE;

    int d = (blockIdx.x * blockDim.x + threadIdx.x) >> 6;
    int lane = threadIdx.x & 63;
    if (d >= NN) return;
    int s0 = row_ptr[d], s1 = row_ptr[d + 1];
    int deg = s1 - s0;
    int base = lane * 8;
    float acc[8] = {0.f, 0.f, 0.f, 0.f, 0.f, 0.f, 0.f, 0.f};

    if (deg <= 64) {
        int sv = 0;
        float av = 0.f;
        if (lane < deg) sv = csr_src[s0 + lane];
        float erd = er[d];
        float v = -1e30f;
        if (lane < deg) {
            float e = el[sv] + erd;
            v = e >= 0.f ? e : 0.2f * e;
        }
        float m = v;
#pragma unroll
        for (int off = 32; off > 0; off >>= 1) m = fmaxf(m, __shfl_xor(m, off));
        float wgt = (lane < deg) ? __expf(v - m) : 0.f;
        float s = wgt;
#pragma unroll
        for (int off = 32; off > 0; off >>= 1) s += __shfl_xor(s, off);
        av = wgt / s;
        int t = 0;
        for (; t + 3 < deg; t += 4) {
            int sA = __shfl(sv, t), sB = __shfl(sv, t + 1);
            int sC = __shfl(sv, t + 2), sD = __shfl(sv, t + 3);
            float aA = __shfl(av, t), aB = __shfl(av, t + 1);
            float aC = __shfl(av, t + 2), aD = __shfl(av, t + 3);
            uint4 hv0 = *(const uint4*)(h + (size_t)sA * NH + base);
            uint4 hv1 = *(const uint4*)(h + (size_t)sB * NH + base);
            uint4 hv2 = *(const uint4*)(h + (size_t)sC * NH + base);
            uint4 hv3 = *(const uint4*)(h + (size_t)sD * NH + base);
            const unsigned short* h0 = (const unsigned short*)&hv0;
            const unsigned short* h1 = (const unsigned short*)&hv1;
            const unsigned short* h2 = (const unsigned short*)&hv2;
            const unsigned short* h3 = (const unsigned short*)&hv3;
#pragma unroll
            for (int k = 0; k < 8; k++)
                acc[k] += aA * bfbits2f(h0[k]) + aB * bfbits2f(h1[k]) + aC * bfbits2f(h2[k]) +
                          aD * bfbits2f(h3[k]);
        }
        for (; t < deg; t++) {
            int sA = __shfl(sv, t);
            float aA = __shfl(av, t);
            uint4 hv0 = *(const uint4*)(h + (size_t)sA * NH + base);
            const unsigned short* h0 = (const unsigned short*)&hv0;
#pragma unroll
            for (int k = 0; k < 8; k++) acc[k] += aA * bfbits2f(h0[k]);
        }
    } else {
        float erd = er[d];
        float m = -1e30f;
        for (int j = s0 + lane; j < s1; j += 64) {
            float e = el[csr_src[j]] + erd;
            e = e >= 0.f ? e : 0.2f * e;
            alpha_tmp[j] = e;
            m = fmaxf(m, e);
        }
#pragma unroll
        for (int off = 32; off > 0; off >>= 1) m = fmaxf(m, __shfl_xor(m, off));
        float s = 0.f;
        for (int j = s0 + lane; j < s1; j += 64) {
            float wv = __expf(alpha_tmp[j] - m);
            alpha_tmp[j] = wv;
            s += wv;
        }
#pragma unroll
        for (int off = 32; off > 0; off >>= 1) s += __shfl_xor(s, off);
        float inv = 1.f / s;
        for (int j0 = 0; j0 < deg; j0 += 64) {
            int cnt = deg - j0;
            if (cnt > 64) cnt = 64;
            int sv = 0;
            float av = 0.f;
            if (lane < cnt) {
                sv = csr_src[s0 + j0 + lane];
                av = alpha_tmp[s0 + j0 + lane] * inv;
            }
            for (int t = 0; t < cnt; t++) {
                int sA = __shfl(sv, t);
                float aA = __shfl(av, t);
                uint4 hv0 = *(const uint4*)(h + (size_t)sA * NH + base);
                const unsigned short* h0 = (const unsigned short*)&hv0;
#pragma unroll
                for (int k = 0; k < 8; k++) acc[k] += aA * bfbits2f(h0[k]);
            }
        }
    }

    float4 b0 = *(const float4*)(bias + base);
    float4 b1 = *(const float4*)(bias + base + 4);
    acc[0] += b0.x; acc[1] += b0.y; acc[2] += b0.z; acc[3] += b0.w;
    acc[4] += b1.x; acc[5] += b1.y; acc[6] += b1.z; acc[7] += b1.w;
    union { __hip_bfloat16 b[8]; uint4 u; } cv;
#pragma unroll
    for (int k = 0; k < 8; k++) cv.b[k] = __float2bfloat16(acc[k]);
    *(uint4*)(gat4 + (size_t)rel * NN * DD + (size_t)d * DD + base) = cv.u;
}

extern "C" void kernel_launch(void* const* d_in, const int* in_sizes, int n_in,
                              void* d_out, int out_size, void* d_ws, size_t ws_size,
                              hipStream_t stream) {
    const float* x = (const float*)d_in[0];
    const int* edges[4] = {(const int*)d_in[1], (const int*)d_in[5], (const int*)d_in[9],
                           (const int*)d_in[13]};
    const float* W[4] = {(const float*)d_in[2], (const float*)d_in[6], (const float*)d_in[10],
                         (const float*)d_in[14]};
    const float* al[4] = {(const float*)d_in[3], (const float*)d_in[7], (const float*)d_in[11],
                          (const float*)d_in[15]};
    const float* ar[4] = {(const float*)d_in[4], (const float*)d_in[8], (const float*)d_in[12],
                          (const float*)d_in[16]};
    const float* Wl = (const float*)d_in[17];
    const float* bias = (const float*)d_in[18];
    float* out = (float*)d_out;

    char* w = (char*)d_ws;
    auto alloc = [&](size_t bytes) {
        char* p = w;
        w += (bytes + 255) & ~(size_t)255;
        return p;
    };
    __hip_bfloat16* x_bf = (__hip_bfloat16*)alloc((size_t)NN * DD * 2);
    __hip_bfloat16* h_all = (__hip_bfloat16*)alloc((size_t)NN * NH * 2);   // [h0..h3|xwl]
    __hip_bfloat16* gat4 = (__hip_bfloat16*)alloc((size_t)4 * NN * DD * 2);
    __hip_bfloat16* t_A = (__hip_bfloat16*)alloc((size_t)NN * DD * 2);
    __hip_bfloat16* t_B = (__hip_bfloat16*)alloc((size_t)NN * DD * 2);
    __hip_bfloat16* Bt_all = (__hip_bfloat16*)alloc((size_t)NH * DD * 2);  // [W0..W3,WlTop]^T
    __hip_bfloat16* WlTb = (__hip_bfloat16*)alloc((size_t)DD * DD * 2);
    float* wal8 = (float*)alloc((size_t)8 * 512 * 4);
    float* el4 = (float*)alloc((size_t)4 * NN * 4);
    float* er4 = (float*)alloc((size_t)4 * NN * 4);
    int* deg4 = (int*)alloc((size_t)4 * NN * 4);
    int* rp4 = (int*)alloc((size_t)4 * (NN + 1) * 4);
    int* cur4 = (int*)alloc((size_t)4 * NN * 4);
    int* csr4 = (int*)alloc((size_t)4 * EE * 4);
    float* alpha4 = (float*)alloc((size_t)4 * EE * 4);

    // L1: convert x, zero deg4, wal8, transpose6 (fused)
    k_fused_pre<<<PRE_CONV + PRE_ZERO + PRE_WAL + PRE_TR, 256, 0, stream>>>(
        x, x_bf, deg4, W[0], W[1], W[2], W[3], al[0], al[1], al[2], al[3], ar[0], ar[1], ar[2],
        ar[3], wal8, Wl, Bt_all, WlTb);

    // L2: count4 + elr8 (fused; both depend only on L1)
    k_fused_mid<<<MID_CNT + NN / 4, 256, 0, stream>>>(edges[0], edges[1], edges[2], edges[3],
                                                      deg4, x_bf, wal8, el4, er4);

    // L3: MEGA-GEMM (+scan4 in tail blocks 800..803)
    k_gemm256<<<GEMM256_BLKS + 4, 512, 0, stream>>>(x_bf, Bt_all, h_all, NH, NN, 10, deg4, rp4,
                                                    cur4);

    // L4: scatter (needs scan4)
    k_scatter4<<<(4 * EE + 255) / 256, 256, 0, stream>>>(edges[0], edges[1], edges[2], edges[3],
                                                         cur4, csr4);

    // L5: batched aggregate (+bias), wave per dst
    dim3 gagg((NN * 64 + 255) / 256, 4);
    k_agg4<<<gagg, 256, 0, stream>>>(rp4, csr4, el4, er4, h_all, bias, gat4, alpha4);

    // L6-9: serial chain
    const int RT128p8 = (((NN + 127) / 128 + 7) / 8) * 8;  // 160
    const int NB = RT128p8 * 4;
    k_gemm512<<<NB, 512, 0, stream>>>(gat4, WlTb, nullptr, h_all, gat4 + (size_t)1 * NN * DD, t_A,
                                      nullptr, DD, NN, 4, 1);
    k_gemm512<<<NB, 512, 0, stream>>>(t_A, WlTb, nullptr, h_all, gat4 + (size_t)2 * NN * DD, t_B,
                                      nullptr, DD, NN, 4, 1);
    k_gemm512<<<NB, 512, 0, stream>>>(t_B, WlTb, nullptr, h_all, gat4 + (size_t)3 * NN * DD, t_A,
                                      nullptr, DD, NN, 4, 1);
    k_gemm512<<<NB, 512, 0, stream>>>(t_A, WlTb, nullptr, h_all, nullptr, nullptr, out, DD, NN, 4,
                                      2);
}

// Round 18
// 495.372 us; speedup vs baseline: 1.2079x; 1.0513x over previous
//
#include <hip/hip_runtime.h>
#include <hip/hip_bf16.h>

#define NN 20000
#define DD 512
#define EE 150000
#define NH 2560  // stacked GEMM width: 4*512 (W_i) + 512 (Wl_top)

typedef __attribute__((ext_vector_type(8))) short short8;
typedef __attribute__((ext_vector_type(4))) float floatx4;

static __device__ __forceinline__ float bfbits2f(unsigned short u) {
    unsigned int x = ((unsigned int)u) << 16;
    return __uint_as_float(x);
}

#define GLOAD_LDS16(g, l)                                                        \
    __builtin_amdgcn_global_load_lds((const __attribute__((address_space(1))) void*)(g), \
                                     (__attribute__((address_space(3))) void*)(l), 16, 0, 0)

// ------- fused L1: convert x, zero deg4, wal8, 6x transpose (R16: launch fusion) ---
#define PRE_CONV 10000
#define PRE_ZERO 313
#define PRE_WAL 64
#define PRE_TR 1536  // 6 mats x 16x16 tiles
__global__ __launch_bounds__(256)
void k_fused_pre(const float* __restrict__ x, __hip_bfloat16* __restrict__ x_bf,
                 int* __restrict__ deg4,
                 const float* __restrict__ W0, const float* __restrict__ W1,
                 const float* __restrict__ W2, const float* __restrict__ W3,
                 const float* __restrict__ al0, const float* __restrict__ al1,
                 const float* __restrict__ al2, const float* __restrict__ al3,
                 const float* __restrict__ ar0, const float* __restrict__ ar1,
                 const float* __restrict__ ar2, const float* __restrict__ ar3,
                 float* __restrict__ wal8, const float* __restrict__ Wl,
                 __hip_bfloat16* __restrict__ Bt_all, __hip_bfloat16* __restrict__ WlTb) {
    int b = blockIdx.x;
    int tid = threadIdx.x;
    if (b < PRE_CONV) {
        int i = b * 256 + tid;
        float4 v = ((const float4*)x)[i];
        union { __hip_bfloat16 bb[4]; ushort4 u; } cv;
        cv.bb[0] = __float2bfloat16(v.x);
        cv.bb[1] = __float2bfloat16(v.y);
        cv.bb[2] = __float2bfloat16(v.z);
        cv.bb[3] = __float2bfloat16(v.w);
        *(ushort4*)(x_bf + 4l * i) = cv.u;
    } else if (b < PRE_CONV + PRE_ZERO) {
        int i = (b - PRE_CONV) * 256 + tid;
        if (i < 4 * NN) deg4[i] = 0;
    } else if (b < PRE_CONV + PRE_ZERO + PRE_WAL) {
        int vk = b - PRE_CONV - PRE_ZERO;
        int v = vk >> 3, kg = vk & 7;
        int rel = v & 3;
        const float* Wp = rel == 0 ? W0 : rel == 1 ? W1 : rel == 2 ? W2 : W3;
        const float* vec;
        if (v < 4) vec = rel == 0 ? al0 : rel == 1 ? al1 : rel == 2 ? al2 : al3;
        else vec = rel == 0 ? ar0 : rel == 1 ? ar1 : rel == 2 ? ar2 : ar3;
        int wave = tid >> 6, lane = tid & 63;
#pragma unroll 1
        for (int i = 0; i < 16; i++) {
            int k = kg * 64 + wave * 16 + i;
            float s = 0.f;
#pragma unroll
            for (int c = 0; c < 8; c++) s += Wp[(size_t)k * 512 + c * 64 + lane] * vec[c * 64 + lane];
#pragma unroll
            for (int off = 32; off > 0; off >>= 1) s += __shfl_xor(s, off);
            if (lane == 0) wal8[v * 512 + k] = s;
        }
    } else {
        // transpose6 re-expressed at 256 threads: 4 rows/thread
        int t = b - PRE_CONV - PRE_ZERO - PRE_WAL;
        int z = t >> 8;            // /256
        int rem = t & 255;
        int by = (rem >> 4) * 32;  // /16
        int bx = (rem & 15) * 32;
        const float* in = z == 0 ? W0 : z == 1 ? W1 : z == 2 ? W2 : z == 3 ? W3
                          : (z == 4 ? Wl : Wl + (size_t)DD * DD);
        __hip_bfloat16* out = z < 5 ? Bt_all + (size_t)z * DD * DD : WlTb;
        __shared__ float tile[32][33];
        int tx = tid & 31, ty0 = tid >> 5;  // ty0 in 0..7
#pragma unroll
        for (int r = 0; r < 4; r++) {
            int row = ty0 + r * 8;
            tile[row][tx] = in[(size_t)(by + row) * 512 + bx + tx];
        }
        __syncthreads();
#pragma unroll
        for (int r = 0; r < 4; r++) {
            int row = ty0 + r * 8;
            out[(size_t)(bx + row) * 512 + by + tx] = __float2bfloat16(tile[tx][row]);
        }
    }
}

// ------- fused L2: count4 + elr8 (both depend only on L1 outputs) ------------------
#define MID_CNT 2344  // ceil(4*EE/256)
__global__ __launch_bounds__(256)
void k_fused_mid(const int* __restrict__ e0, const int* __restrict__ e1,
                 const int* __restrict__ e2, const int* __restrict__ e3,
                 int* __restrict__ deg4, const __hip_bfloat16* __restrict__ x_bf,
                 const float* __restrict__ wal8, float* __restrict__ el4,
                 float* __restrict__ er4) {
    int b = blockIdx.x;
    int tid = threadIdx.x;
    if (b < MID_CNT) {
        int g = b * 256 + tid;
        if (g >= 4 * EE) return;
        int rel = g / EE;
        int e = g - rel * EE;
        const int* ed = rel == 0 ? e0 : rel == 1 ? e1 : rel == 2 ? e2 : e3;
        atomicAdd(&deg4[rel * NN + ed[EE + e]], 1);
        return;
    }
    int wave = tid >> 6, lane = tid & 63;
    int r = (b - MID_CNT) * 4 + wave;
    uint4 xv = *(const uint4*)(x_bf + (size_t)r * DD + lane * 8);
    const unsigned short* xs = (const unsigned short*)&xv;
    float xf[8];
#pragma unroll
    for (int j = 0; j < 8; j++) xf[j] = bfbits2f(xs[j]);
    float s[8];
#pragma unroll
    for (int v = 0; v < 8; v++) {
        const float* wp = wal8 + v * 512 + lane * 8;
        s[v] = xf[0] * wp[0] + xf[1] * wp[1] + xf[2] * wp[2] + xf[3] * wp[3] +
               xf[4] * wp[4] + xf[5] * wp[5] + xf[6] * wp[6] + xf[7] * wp[7];
    }
#pragma unroll
    for (int off = 32; off > 0; off >>= 1)
#pragma unroll
        for (int v = 0; v < 8; v++) s[v] += __shfl_xor(s[v], off);
    if (lane == 0) {
#pragma unroll
        for (int rel = 0; rel < 4; rel++) {
            el4[rel * NN + r] = s[rel];
            er4[rel * NN + r] = s[4 + rel];
        }
    }
}

// ---------------- GEMM (chain): 128x128, BK=64, R3 schedule + COALESCED staging ----
// R9-verified WIN. R15 A/B: dbuf at 128^2 = +62us regression. Single-buffer keeper.
// mode 1: t_next = bf16(relu(C + xwl) + gnext)   (chain mid)
// mode 2: outf = relu(C + xwl) fp32              (chain last)
__global__ __launch_bounds__(512)
void k_gemm512(const __hip_bfloat16* __restrict__ A, const __hip_bfloat16* __restrict__ Bt,
               __hip_bfloat16* __restrict__ Cb, const __hip_bfloat16* __restrict__ xwl,
               const __hip_bfloat16* __restrict__ gnext, __hip_bfloat16* __restrict__ t_next,
               float* __restrict__ outf, int c_ld, int M, int CT, int mode) {
    const int RT = (M + 127) >> 7;
    const int xcd = blockIdx.x & 7;
    const int k_ = blockIdx.x >> 3;
    const int ctile = k_ % CT;
    const int rtile = (k_ / CT) * 8 + xcd;
    if (rtile >= RT) return;

    __shared__ __hip_bfloat16 As[128 * 64];  // 16 KB; row-major [128][64], chunks XOR-swz
    __shared__ __hip_bfloat16 Bs[128 * 64];  // 16 KB
    const int tid = threadIdx.x;
    const int lane = tid & 63;
    const int wave = tid >> 6;
    const int row0 = rtile * 128;
    const int col0 = ctile * 128;
    const int wm = (wave >> 2) * 64;   // 0 or 64
    const int wn = (wave & 3) * 32;    // 0,32,64,96
    const int q8 = lane >> 4;
    const int l15 = lane & 15;
    const int l7 = l15 & 7;

    const int rsub = lane >> 3;
    const int csw = (lane & 7) ^ rsub;
    const __hip_bfloat16* aBase = A + (size_t)csw * 8;
    const __hip_bfloat16* bBase = Bt + (size_t)csw * 8;

    floatx4 acc[4][2];
#pragma unroll
    for (int a = 0; a < 4; a++)
#pragma unroll
        for (int b = 0; b < 2; b++) acc[a][b] = (floatx4){0.f, 0.f, 0.f, 0.f};

    for (int k0 = 0; k0 < DD; k0 += 64) {
        __syncthreads();
#pragma unroll
        for (int j = 0; j < 2; j++) {
            int arow = row0 + wave * 16 + j * 8 + rsub;
            if (arow >= M) arow = M - 1;
            int brow = col0 + wave * 16 + j * 8 + rsub;
            GLOAD_LDS16(aBase + (size_t)arow * DD + k0,
                        As + ((wave * 16 + j * 8) * 64) + (size_t)lane * 8);
            GLOAD_LDS16(bBase + (size_t)brow * DD + k0,
                        Bs + ((wave * 16 + j * 8) * 64) + (size_t)lane * 8);
        }
        __syncthreads();
#pragma unroll
        for (int kk = 0; kk < 2; kk++) {
            const int cp = ((kk * 4 + q8) ^ l7) * 8;
            short8 af[4], bf[2];
#pragma unroll
            for (int mi = 0; mi < 4; mi++)
                af[mi] = *(const short8*)(As + (size_t)(wm + mi * 16 + l15) * 64 + cp);
#pragma unroll
            for (int ni = 0; ni < 2; ni++)
                bf[ni] = *(const short8*)(Bs + (size_t)(wn + ni * 16 + l15) * 64 + cp);
#pragma unroll
            for (int mi = 0; mi < 4; mi++)
#pragma unroll
                for (int ni = 0; ni < 2; ni++)
                    acc[mi][ni] = __builtin_amdgcn_mfma_f32_16x16x32_bf16(af[mi], bf[ni],
                                                                          acc[mi][ni], 0, 0, 0);
        }
    }

#pragma unroll
    for (int mi = 0; mi < 4; mi++)
#pragma unroll
        for (int ni = 0; ni < 2; ni++)
#pragma unroll
            for (int r = 0; r < 4; r++) {
                int grow = row0 + wm + mi * 16 + q8 * 4 + r;
                int gcol = col0 + wn + ni * 16 + l15;
                if (grow < M) {
                    float v = acc[mi][ni][r];
                    if (mode == 0) {
                        Cb[(size_t)grow * c_ld + gcol] = __float2bfloat16(v);
                    } else {
                        v += bfbits2f(
                            *(const unsigned short*)(xwl + (size_t)grow * NH + 2048 + gcol));
                        v = v > 0.f ? v : 0.f;
                        size_t idx = (size_t)grow * DD + gcol;
                        if (mode == 1) {
                            v += bfbits2f(*(const unsigned short*)(gnext + idx));
                            t_next[idx] = __float2bfloat16(v);
                        } else {
                            outf[idx] = v;
                        }
                    }
                }
            }
}

// ---------------- MEGA-GEMM: 256x256, BK=64, dbuf 2-phase, COALESCED+SWIZZLED ------
// R8 WIN (frozen). R17: scan4 in tail blocks extended makespan (~13us, occ 18.6->11.9)
// -> R18: scan blocks moved to FRONT (idx 0..3); they finish in round 1 and their
// CUs rejoin the gemm pool. gemm uses bb = blockIdx.x - 4 (same swizzle on 0..799).
#define SCAN_BLKS 4
__global__ __launch_bounds__(512)
void k_gemm256(const __hip_bfloat16* __restrict__ A, const __hip_bfloat16* __restrict__ Bt,
               __hip_bfloat16* __restrict__ Cb, int c_ld, int M, int CT,
               const int* __restrict__ deg4, int* __restrict__ rp4, int* __restrict__ cur4) {
    if (blockIdx.x < SCAN_BLKS) {
        // scan4 @512 threads
        const int rel = blockIdx.x;
        const int* deg = deg4 + rel * NN;
        int* row_ptr = rp4 + rel * (NN + 1);
        int* cursor = cur4 + rel * NN;
        __shared__ int sm[512];
        int t = threadIdx.x;
        const int CH = 40;
        int begin = t * CH;
        int end = begin + CH;
        if (end > NN) end = NN;
        int s = 0;
        if (begin < NN)
            for (int i = begin; i < end; i++) s += deg[i];
        sm[t] = s;
        __syncthreads();
        for (int off = 1; off < 512; off <<= 1) {
            int v = (t >= off) ? sm[t - off] : 0;
            __syncthreads();
            sm[t] += v;
            __syncthreads();
        }
        int run = sm[t] - s;
        if (begin < NN) {
            for (int i = begin; i < end; i++) {
                row_ptr[i] = run;
                cursor[i] = run;
                run += deg[i];
            }
            if (end == NN) row_ptr[NN] = run;
        }
        return;
    }
    const int bb = blockIdx.x - SCAN_BLKS;  // 0..799
    const int RT = (M + 255) >> 8;
    const int xcd = bb & 7;
    const int k_ = bb >> 3;
    const int ctile = k_ % CT;
    const int rtile = (k_ / CT) * 8 + xcd;
    if (rtile >= RT) return;

    __shared__ __hip_bfloat16 As0[256 * 64];  // 32 KB each; row-major, chunks XOR-swz
    __shared__ __hip_bfloat16 Bs0[256 * 64];
    __shared__ __hip_bfloat16 As1[256 * 64];
    __shared__ __hip_bfloat16 Bs1[256 * 64];
    const int tid = threadIdx.x;
    const int lane = tid & 63;
    const int wave = tid >> 6;
    const int row0 = rtile * 256;
    const int col0 = ctile * 256;
    const int wm = (wave >> 2) * 128;  // 0 or 128
    const int wn = (wave & 3) * 64;    // 0,64,128,192
    const int q8 = lane >> 4;
    const int l15 = lane & 15;
    const int l7 = l15 & 7;

    const int rsub = lane >> 3;
    const int csw = (lane & 7) ^ rsub;
    const __hip_bfloat16* aBase = A + (size_t)csw * 8;
    const __hip_bfloat16* bBase = Bt + (size_t)csw * 8;

#define STAGE256(k0, AL, BL)                                                              \
    {                                                                                     \
        _Pragma("unroll") for (int j = 0; j < 4; j++) {                                   \
            int arow = row0 + wave * 32 + j * 8 + rsub;                                   \
            if (arow >= M) arow = M - 1;                                                  \
            int brow = col0 + wave * 32 + j * 8 + rsub;                                   \
            GLOAD_LDS16(aBase + (size_t)arow * DD + (k0),                                 \
                        (AL) + ((wave * 32 + j * 8) * 64) + (size_t)lane * 8);            \
            GLOAD_LDS16(bBase + (size_t)brow * DD + (k0),                                 \
                        (BL) + ((wave * 32 + j * 8) * 64) + (size_t)lane * 8);            \
        }                                                                                 \
    }

#define COMPUTE256(AS, BS)                                                          \
    {                                                                               \
        _Pragma("unroll") for (int kk = 0; kk < 2; kk++) {                          \
            const int cp = ((kk * 4 + q8) ^ l7) * 8;                                \
            short8 af[8], bfr[4];                                                   \
            _Pragma("unroll") for (int mi = 0; mi < 8; mi++)                        \
                af[mi] = *(const short8*)((AS) +                                    \
                    (size_t)(wm + mi * 16 + l15) * 64 + cp);                        \
            _Pragma("unroll") for (int ni = 0; ni < 4; ni++)                        \
                bfr[ni] = *(const short8*)((BS) +                                   \
                    (size_t)(wn + ni * 16 + l15) * 64 + cp);                        \
            _Pragma("unroll") for (int mi = 0; mi < 8; mi++)                        \
                _Pragma("unroll") for (int ni = 0; ni < 4; ni++)                    \
                    acc[mi][ni] = __builtin_amdgcn_mfma_f32_16x16x32_bf16(          \
                        af[mi], bfr[ni], acc[mi][ni], 0, 0, 0);                     \
        }                                                                           \
    }

    floatx4 acc[8][4];
#pragma unroll
    for (int a = 0; a < 8; a++)
#pragma unroll
        for (int b = 0; b < 4; b++) acc[a][b] = (floatx4){0.f, 0.f, 0.f, 0.f};

    STAGE256(0, As0, Bs0)
    __syncthreads();

#pragma unroll 1
    for (int t0 = 0; t0 < 8; t0 += 2) {
        STAGE256(t0 * 64 + 64, As1, Bs1)
        COMPUTE256(As0, Bs0)
        __syncthreads();
        if (t0 < 6) STAGE256(t0 * 64 + 128, As0, Bs0)
        COMPUTE256(As1, Bs1)
        __syncthreads();
    }
#undef STAGE256
#undef COMPUTE256

#pragma unroll
    for (int mi = 0; mi < 8; mi++)
#pragma unroll
        for (int ni = 0; ni < 4; ni++)
#pragma unroll
            for (int r = 0; r < 4; r++) {
                int grow = row0 + wm + mi * 16 + q8 * 4 + r;
                int gcol = col0 + wn + ni * 16 + l15;
                if (grow < M) Cb[(size_t)grow * c_ld + gcol] = __float2bfloat16(acc[mi][ni][r]);
            }
}

// ---------------- scatter (batched over 4 relations) ----------------
__global__ void k_scatter4(const int* __restrict__ e0, const int* __restrict__ e1,
                           const int* __restrict__ e2, const int* __restrict__ e3,
                           int* __restrict__ cur4, int* __restrict__ csr4) {
    int g = blockIdx.x * blockDim.x + threadIdx.x;
    if (g >= 4 * EE) return;
    int rel = g / EE;
    int e = g - rel * EE;
    const int* ed = rel == 0 ? e0 : rel == 1 ? e1 : rel == 2 ? e2 : e3;
    int dst = ed[EE + e];
    int pos = atomicAdd(&cur4[rel * NN + dst], 1);
    csr4[rel * EE + pos] = ed[e];
}

// ---------------- BATCHED edge-softmax + aggregate (+bias), wave per dst ----------
// R9 version (86.6us, occupancy 74%): at the random-gather BW floor (~4 TB/s).
__global__ __launch_bounds__(256)
void k_agg4(const int* __restrict__ rp4, const int* __restrict__ csr4,
            const float* __restrict__ el4, const float* __restrict__ er4,
            const __hip_bfloat16* __restrict__ h_all, const float* __restrict__ bias,
            __hip_bfloat16* __restrict__ gat4, float* __restrict__ alpha4) {
    const int rel = blockIdx.y;
    const int* row_ptr = rp4 + rel * (NN + 1);
    const int* csr_src = csr4 + (size_t)rel * EE;
    const float* el = el4 + rel * NN;
    const float* er = er4 + rel * NN;
    const __hip_bfloat16* h = h_all + (size_t)rel * 512;
    float* alpha_tmp = alpha4 + (size_t)rel * EE;

    int d = (blockIdx.x * blockDim.x + threadIdx.x) >> 6;
    int lane = threadIdx.x & 63;
    if (d >= NN) return;
    int s0 = row_ptr[d], s1 = row_ptr[d + 1];
    int deg = s1 - s0;
    int base = lane * 8;
    float acc[8] = {0.f, 0.f, 0.f, 0.f, 0.f, 0.f, 0.f, 0.f};

    if (deg <= 64) {
        int sv = 0;
        float av = 0.f;
        if (lane < deg) sv = csr_src[s0 + lane];
        float erd = er[d];
        float v = -1e30f;
        if (lane < deg) {
            float e = el[sv] + erd;
            v = e >= 0.f ? e : 0.2f * e;
        }
        float m = v;
#pragma unroll
        for (int off = 32; off > 0; off >>= 1) m = fmaxf(m, __shfl_xor(m, off));
        float wgt = (lane < deg) ? __expf(v - m) : 0.f;
        float s = wgt;
#pragma unroll
        for (int off = 32; off > 0; off >>= 1) s += __shfl_xor(s, off);
        av = wgt / s;
        int t = 0;
        for (; t + 3 < deg; t += 4) {
            int sA = __shfl(sv, t), sB = __shfl(sv, t + 1);
            int sC = __shfl(sv, t + 2), sD = __shfl(sv, t + 3);
            float aA = __shfl(av, t), aB = __shfl(av, t + 1);
            float aC = __shfl(av, t + 2), aD = __shfl(av, t + 3);
            uint4 hv0 = *(const uint4*)(h + (size_t)sA * NH + base);
            uint4 hv1 = *(const uint4*)(h + (size_t)sB * NH + base);
            uint4 hv2 = *(const uint4*)(h + (size_t)sC * NH + base);
            uint4 hv3 = *(const uint4*)(h + (size_t)sD * NH + base);
            const unsigned short* h0 = (const unsigned short*)&hv0;
            const unsigned short* h1 = (const unsigned short*)&hv1;
            const unsigned short* h2 = (const unsigned short*)&hv2;
            const unsigned short* h3 = (const unsigned short*)&hv3;
#pragma unroll
            for (int k = 0; k < 8; k++)
                acc[k] += aA * bfbits2f(h0[k]) + aB * bfbits2f(h1[k]) + aC * bfbits2f(h2[k]) +
                          aD * bfbits2f(h3[k]);
        }
        for (; t < deg; t++) {
            int sA = __shfl(sv, t);
            float aA = __shfl(av, t);
            uint4 hv0 = *(const uint4*)(h + (size_t)sA * NH + base);
            const unsigned short* h0 = (const unsigned short*)&hv0;
#pragma unroll
            for (int k = 0; k < 8; k++) acc[k] += aA * bfbits2f(h0[k]);
        }
    } else {
        float erd = er[d];
        float m = -1e30f;
        for (int j = s0 + lane; j < s1; j += 64) {
            float e = el[csr_src[j]] + erd;
            e = e >= 0.f ? e : 0.2f * e;
            alpha_tmp[j] = e;
            m = fmaxf(m, e);
        }
#pragma unroll
        for (int off = 32; off > 0; off >>= 1) m = fmaxf(m, __shfl_xor(m, off));
        float s = 0.f;
        for (int j = s0 + lane; j < s1; j += 64) {
            float wv = __expf(alpha_tmp[j] - m);
            alpha_tmp[j] = wv;
            s += wv;
        }
#pragma unroll
        for (int off = 32; off > 0; off >>= 1) s += __shfl_xor(s, off);
        float inv = 1.f / s;
        for (int j0 = 0; j0 < deg; j0 += 64) {
            int cnt = deg - j0;
            if (cnt > 64) cnt = 64;
            int sv = 0;
            float av = 0.f;
            if (lane < cnt) {
                sv = csr_src[s0 + j0 + lane];
                av = alpha_tmp[s0 + j0 + lane] * inv;
            }
            for (int t = 0; t < cnt; t++) {
                int sA = __shfl(sv, t);
                float aA = __shfl(av, t);
                uint4 hv0 = *(const uint4*)(h + (size_t)sA * NH + base);
                const unsigned short* h0 = (const unsigned short*)&hv0;
#pragma unroll
                for (int k = 0; k < 8; k++) acc[k] += aA * bfbits2f(h0[k]);
            }
        }
    }

    float4 b0 = *(const float4*)(bias + base);
    float4 b1 = *(const float4*)(bias + base + 4);
    acc[0] += b0.x; acc[1] += b0.y; acc[2] += b0.z; acc[3] += b0.w;
    acc[4] += b1.x; acc[5] += b1.y; acc[6] += b1.z; acc[7] += b1.w;
    union { __hip_bfloat16 b[8]; uint4 u; } cv;
#pragma unroll
    for (int k = 0; k < 8; k++) cv.b[k] = __float2bfloat16(acc[k]);
    *(uint4*)(gat4 + (size_t)rel * NN * DD + (size_t)d * DD + base) = cv.u;
}

extern "C" void kernel_launch(void* const* d_in, const int* in_sizes, int n_in,
                              void* d_out, int out_size, void* d_ws, size_t ws_size,
                              hipStream_t stream) {
    const float* x = (const float*)d_in[0];
    const int* edges[4] = {(const int*)d_in[1], (const int*)d_in[5], (const int*)d_in[9],
                           (const int*)d_in[13]};
    const float* W[4] = {(const float*)d_in[2], (const float*)d_in[6], (const float*)d_in[10],
                         (const float*)d_in[14]};
    const float* al[4] = {(const float*)d_in[3], (const float*)d_in[7], (const float*)d_in[11],
                          (const float*)d_in[15]};
    const float* ar[4] = {(const float*)d_in[4], (const float*)d_in[8], (const float*)d_in[12],
                          (const float*)d_in[16]};
    const float* Wl = (const float*)d_in[17];
    const float* bias = (const float*)d_in[18];
    float* out = (float*)d_out;

    char* w = (char*)d_ws;
    auto alloc = [&](size_t bytes) {
        char* p = w;
        w += (bytes + 255) & ~(size_t)255;
        return p;
    };
    __hip_bfloat16* x_bf = (__hip_bfloat16*)alloc((size_t)NN * DD * 2);
    __hip_bfloat16* h_all = (__hip_bfloat16*)alloc((size_t)NN * NH * 2);   // [h0..h3|xwl]
    __hip_bfloat16* gat4 = (__hip_bfloat16*)alloc((size_t)4 * NN * DD * 2);
    __hip_bfloat16* t_A = (__hip_bfloat16*)alloc((size_t)NN * DD * 2);
    __hip_bfloat16* t_B = (__hip_bfloat16*)alloc((size_t)NN * DD * 2);
    __hip_bfloat16* Bt_all = (__hip_bfloat16*)alloc((size_t)NH * DD * 2);  // [W0..W3,WlTop]^T
    __hip_bfloat16* WlTb = (__hip_bfloat16*)alloc((size_t)DD * DD * 2);
    float* wal8 = (float*)alloc((size_t)8 * 512 * 4);
    float* el4 = (float*)alloc((size_t)4 * NN * 4);
    float* er4 = (float*)alloc((size_t)4 * NN * 4);
    int* deg4 = (int*)alloc((size_t)4 * NN * 4);
    int* rp4 = (int*)alloc((size_t)4 * (NN + 1) * 4);
    int* cur4 = (int*)alloc((size_t)4 * NN * 4);
    int* csr4 = (int*)alloc((size_t)4 * EE * 4);
    float* alpha4 = (float*)alloc((size_t)4 * EE * 4);

    // L1: convert x, zero deg4, wal8, transpose6 (fused)
    k_fused_pre<<<PRE_CONV + PRE_ZERO + PRE_WAL + PRE_TR, 256, 0, stream>>>(
        x, x_bf, deg4, W[0], W[1], W[2], W[3], al[0], al[1], al[2], al[3], ar[0], ar[1], ar[2],
        ar[3], wal8, Wl, Bt_all, WlTb);

    // L2: count4 + elr8 (fused; both depend only on L1)
    k_fused_mid<<<MID_CNT + NN / 4, 256, 0, stream>>>(edges[0], edges[1], edges[2], edges[3],
                                                      deg4, x_bf, wal8, el4, er4);

    // L3: MEGA-GEMM (scan4 in FRONT blocks 0..3; gemm in 4..803)
    k_gemm256<<<SCAN_BLKS + 800, 512, 0, stream>>>(x_bf, Bt_all, h_all, NH, NN, 10, deg4, rp4,
                                                   cur4);

    // L4: scatter (needs scan4)
    k_scatter4<<<(4 * EE + 255) / 256, 256, 0, stream>>>(edges[0], edges[1], edges[2], edges[3],
                                                         cur4, csr4);

    // L5: batched aggregate (+bias), wave per dst
    dim3 gagg((NN * 64 + 255) / 256, 4);
    k_agg4<<<gagg, 256, 0, stream>>>(rp4, csr4, el4, er4, h_all, bias, gat4, alpha4);

    // L6-9: serial chain
    const int RT128p8 = (((NN + 127) / 128 + 7) / 8) * 8;  // 160
    const int NB = RT128p8 * 4;
    k_gemm512<<<NB, 512, 0, stream>>>(gat4, WlTb, nullptr, h_all, gat4 + (size_t)1 * NN * DD, t_A,
                                      nullptr, DD, NN, 4, 1);
    k_gemm512<<<NB, 512, 0, stream>>>(t_A, WlTb, nullptr, h_all, gat4 + (size_t)2 * NN * DD, t_B,
                                      nullptr, DD, NN, 4, 1);
    k_gemm512<<<NB, 512, 0, stream>>>(t_B, WlTb, nullptr, h_all, gat4 + (size_t)3 * NN * DD, t_A,
                                      nullptr, DD, NN, 4, 1);
    k_gemm512<<<NB, 512, 0, stream>>>(t_A, WlTb, nullptr, h_all, nullptr, nullptr, out, DD, NN, 4,
                                      2);
}